// Round 4
// baseline (348.854 us; speedup 1.0000x reference)
//
#include <hip/hip_runtime.h>
#include <math.h>

using f32x4  = __attribute__((ext_vector_type(4))) float;
using bf16x8 = __attribute__((ext_vector_type(8))) short;
using u16x8  = __attribute__((ext_vector_type(8))) unsigned short;
using u16x4  = __attribute__((ext_vector_type(4))) unsigned short;

static __device__ __forceinline__ unsigned short f2bf(float f) {
  unsigned int u = __builtin_bit_cast(unsigned int, f);
  u += 0x7FFFu + ((u >> 16) & 1u);
  return (unsigned short)(u >> 16);
}
static __device__ __forceinline__ float bf2f(unsigned short h) {
  unsigned int u = ((unsigned int)h) << 16;
  return __builtin_bit_cast(float, u);
}

// async global->LDS, 16B per lane. LDS dest is wave-uniform base; HW appends
// lane*16.
static __device__ __forceinline__ void gll16(const void* g, void* l) {
  using GPtr = const unsigned int __attribute__((address_space(1)))*;
  using LPtr = unsigned int __attribute__((address_space(3)))*;
  __builtin_amdgcn_global_load_lds((GPtr)(unsigned long long)g,
                                   (LPtr)(unsigned)(unsigned long long)l,
                                   16, 0, 0);
}

// Stage one [128][64] bf16 tile with XOR-swizzled layout:
// LDS[row][slot] (slot = 16B unit) holds global column-slot (slot ^ (row&7)).
// Linear LDS dest + pre-swizzled global source column (rule #21).
// Wave w stages rows [32w, 32w+32).
static __device__ __forceinline__ void stage64(unsigned short* sdst,
                                               const unsigned short* g,
                                               size_t ld, int k0, int wave,
                                               int lane) {
  const int r = lane >> 3;                  // 0..7 row within octet
  const int c8 = lane & 7;                  // dest 16B slot 0..7
  const int scol = (c8 ^ r) << 3;           // pre-swizzled source column (elems)
#pragma unroll
  for (int i = 0; i < 4; ++i) {
    const unsigned short* gp = g + (size_t)(wave * 32 + i * 8 + r) * ld + (k0 + scol);
    unsigned short* lp = sdst + wave * 2048 + i * 512;  // wave-uniform
    gll16(gp, lp);
  }
}

// Swizzled fragment read: row-major [128][64], element (row, kko..kko+7).
static __device__ __forceinline__ bf16x8 frag_ld(const unsigned short* s,
                                                 int row, int kko) {
  return *(const bf16x8*)&s[row * 64 + (kko ^ ((row & 7) << 3))];
}

// ---------------------------------------------------------------------------
// W [1024 i][1024 o] f32  ->  WT_hi/WT_lo [1024 o][1024 i] bf16 (transposed)
// z order: 0=K, 1=Q, 2=V.
// ---------------------------------------------------------------------------
__global__ __launch_bounds__(256) void convert_w_kernel(
    const float* __restrict__ Wk, const float* __restrict__ Wq,
    const float* __restrict__ Wv, unsigned short* __restrict__ WThi,
    unsigned short* __restrict__ WTlo) {
  __shared__ float sW[64][65];
  const int z = blockIdx.z;
  const float* W = (z == 0) ? Wk : (z == 1) ? Wq : Wv;
  unsigned short* oh = WThi + (size_t)z * 1024 * 1024;
  unsigned short* ol = WTlo + (size_t)z * 1024 * 1024;
  const int ti = blockIdx.x * 64;
  const int tj = blockIdx.y * 64;
  const int tid = threadIdx.x;
#pragma unroll
  for (int it = 0; it < 4; ++it) {
    int idx = tid + it * 256;
    int r = idx >> 4, c = (idx & 15) << 2;
    f32x4 v = *(const f32x4*)&W[(size_t)(ti + r) * 1024 + tj + c];
    sW[r][c] = v[0]; sW[r][c + 1] = v[1]; sW[r][c + 2] = v[2]; sW[r][c + 3] = v[3];
  }
  __syncthreads();
#pragma unroll
  for (int it = 0; it < 4; ++it) {
    int idx = tid + it * 256;
    int ro = idx >> 4, ci = (idx & 15) << 2;
    u16x4 h, l;
#pragma unroll
    for (int e = 0; e < 4; ++e) {
      float v = sW[ci + e][ro];
      unsigned short hh = f2bf(v);
      h[e] = hh;
      l[e] = f2bf(v - bf2f(hh));
    }
    *(u16x4*)&oh[(size_t)(tj + ro) * 1024 + ti + ci] = h;
    *(u16x4*)&ol[(size_t)(tj + ro) * 1024 + ti + ci] = l;
  }
}

// ---------------------------------------------------------------------------
// X [8192 x 1024] f32 -> Xh (+Xl for z<2) bf16, same layout.
// z: 0=keys, 1=queries, 2=values. Xl slot = z (z<2 only).
// ---------------------------------------------------------------------------
__global__ __launch_bounds__(256) void convert_x_kernel(
    const float* __restrict__ Xk, const float* __restrict__ Xq,
    const float* __restrict__ Xv, unsigned short* __restrict__ H,
    unsigned short* __restrict__ L) {
  const int z = blockIdx.z;
  const float* X = (z == 0) ? Xk : (z == 1) ? Xq : Xv;
  const size_t base = ((size_t)blockIdx.x * 256 + threadIdx.x) * 8;
  float av[8];
  *(f32x4*)&av[0] = *(const f32x4*)&X[base];
  *(f32x4*)&av[4] = *(const f32x4*)&X[base + 4];
  u16x8 h, l;
#pragma unroll
  for (int e = 0; e < 8; ++e) {
    unsigned short hh = f2bf(av[e]);
    h[e] = hh;
    l[e] = f2bf(av[e] - bf2f(hh));
  }
  *(u16x8*)&H[(size_t)z * 8388608 + base] = h;
  if (z < 2) *(u16x8*)&L[(size_t)z * 8388608 + base] = l;
}

// ---------------------------------------------------------------------------
// Unified split-bf16 GEMM: 128x128 tile, BK=64, 4 waves, global_load_lds
// staging into XOR-swizzled [128][64] LDS tiles, 2 barriers per K-step.
// C = A * B^T, A rows = out rows, B rows = out cols, both K-major.
// NTERMS: 3 = AhBh+AhBl+AlBh ; 2 = AhBh+AhBl ; 1 = AhBh.
// B-lo is NOT staged in LDS: read direct global->reg at loop top (L2/L3
// resident; no barrier dependency) -> LDS 48KB for 3-term = 3 blocks/CU.
// EPI: 0 = f32 C ; 1 = bf16 hi+lo ; 2 = bf16 hi.
// PACKED: blockIdx.x is a packed lower-triangle tile index.
// PVK: K-loop ends at (bm+1)*128.
// ---------------------------------------------------------------------------
template <int NTERMS, int EPI, bool PACKED, bool PVK>
__global__ __launch_bounds__(256, 2) void gemm3_kernel(
    const unsigned short* __restrict__ Ah, const unsigned short* __restrict__ Al,
    const unsigned short* __restrict__ Bh, const unsigned short* __restrict__ Bl,
    size_t lda, size_t ldb, int K,
    float* __restrict__ Cf, unsigned short* __restrict__ Ch,
    unsigned short* __restrict__ Cl, size_t ldc,
    size_t abatch, size_t bbatch, size_t cbatch) {
  constexpr int NTILES = (NTERMS == 3) ? 3 : 2;
  __shared__ unsigned short smem[NTILES * 8192];
  int bm, bn;
  if constexpr (PACKED) {
    const int t = blockIdx.x;
    bm = (int)((sqrtf(8.f * (float)t + 1.f) - 1.f) * 0.5f);
    while ((bm + 1) * (bm + 2) / 2 <= t) ++bm;
    while (bm * (bm + 1) / 2 > t) --bm;
    bn = t - bm * (bm + 1) / 2;
  } else {
    bn = blockIdx.x;
    bm = blockIdx.y;
  }
  const int b = blockIdx.z;
  const int tid = threadIdx.x, lane = tid & 63, wave = tid >> 6;
  unsigned short* sAh = smem;
  unsigned short* sBh = smem + 8192;
  unsigned short* sAl = smem + 16384;  // NTERMS == 3 only
  const unsigned short* gA = Ah + abatch * b + (size_t)(bm * 128) * lda;
  const unsigned short* gB = Bh + bbatch * b + (size_t)(bn * 128) * ldb;
  const unsigned short* gAl2 =
      (NTERMS == 3) ? Al + abatch * b + (size_t)(bm * 128) * lda : nullptr;
  const unsigned short* gBl2 =
      (NTERMS >= 2) ? Bl + bbatch * b + (size_t)(bn * 128) * ldb : nullptr;
  const int kend = PVK ? (bm + 1) * 128 : K;
  f32x4 acc[4][4] = {};
  const int wr = (wave >> 1) << 6, wc = (wave & 1) << 6;
  const int frow = lane & 15, koff = (lane >> 4) << 3;
  for (int k0 = 0; k0 < kend; k0 += 64) {
    // Direct global->reg B-lo fragment loads: no LDS, no barrier dependency.
    // Issued before staging so latency hides under stage64 + barrier.
    bf16x8 dBl[2][4];
    if constexpr (NTERMS >= 2) {
#pragma unroll
      for (int h = 0; h < 2; ++h)
#pragma unroll
        for (int j = 0; j < 4; ++j)
          dBl[h][j] = *(const bf16x8*)&gBl2[(size_t)(wc + j * 16 + frow) * ldb +
                                            (k0 + h * 32 + koff)];
    }
    __syncthreads();  // all waves done reading previous tile
    stage64(sAh, gA, lda, k0, wave, lane);
    stage64(sBh, gB, ldb, k0, wave, lane);
    if constexpr (NTERMS == 3) stage64(sAl, gAl2, lda, k0, wave, lane);
    __syncthreads();  // staging complete
#pragma unroll
    for (int kk = 0; kk < 64; kk += 32) {
      const int kko = kk + koff;
      bf16x8 fBh[4];
#pragma unroll
      for (int j = 0; j < 4; ++j) fBh[j] = frag_ld(sBh, wc + j * 16 + frow, kko);
#pragma unroll
      for (int i = 0; i < 4; ++i) {
        const bf16x8 ah = frag_ld(sAh, wr + i * 16 + frow, kko);
        bf16x8 al = {};
        if constexpr (NTERMS == 3) al = frag_ld(sAl, wr + i * 16 + frow, kko);
#pragma unroll
        for (int j = 0; j < 4; ++j) {
          acc[i][j] = __builtin_amdgcn_mfma_f32_16x16x32_bf16(ah, fBh[j], acc[i][j], 0, 0, 0);
          if constexpr (NTERMS >= 2)
            acc[i][j] = __builtin_amdgcn_mfma_f32_16x16x32_bf16(ah, dBl[kk >> 5][j], acc[i][j], 0, 0, 0);
          if constexpr (NTERMS == 3)
            acc[i][j] = __builtin_amdgcn_mfma_f32_16x16x32_bf16(al, fBh[j], acc[i][j], 0, 0, 0);
        }
      }
    }
  }
  const int erow = bm * 128 + wr + ((lane >> 4) << 2);
  const int ecol = bn * 128 + wc + frow;
  if constexpr (EPI == 0) {
    float* C = Cf + cbatch * b;
#pragma unroll
    for (int i = 0; i < 4; ++i)
#pragma unroll
      for (int j = 0; j < 4; ++j)
#pragma unroll
        for (int e = 0; e < 4; ++e)
          C[(size_t)(erow + i * 16 + e) * ldc + (ecol + j * 16)] = acc[i][j][e];
  } else {
    unsigned short* Cho = Ch + cbatch * b;
    unsigned short* Clo = (EPI == 1) ? Cl + cbatch * b : nullptr;
#pragma unroll
    for (int i = 0; i < 4; ++i)
#pragma unroll
      for (int j = 0; j < 4; ++j)
#pragma unroll
        for (int e = 0; e < 4; ++e) {
          size_t off = (size_t)(erow + i * 16 + e) * ldc + (ecol + j * 16);
          float v = acc[i][j][e];
          unsigned short hh = f2bf(v);
          Cho[off] = hh;
          if constexpr (EPI == 1) Clo[off] = f2bf(v - bf2f(hh));
        }
  }
}

// ---------------------------------------------------------------------------
// V [b][2048 s][1024 o] bf16 -> VT [b][1024 o][2048 s] bf16
// ---------------------------------------------------------------------------
__global__ __launch_bounds__(256) void transpose_v_kernel(
    const unsigned short* __restrict__ V, unsigned short* __restrict__ VT) {
  __shared__ unsigned short sV[64][72];
  const int ox = blockIdx.x, sy = blockIdx.y, b = blockIdx.z;
  const int tid = threadIdx.x;
#pragma unroll
  for (int it = 0; it < 2; ++it) {
    int idx = tid + it * 256;
    int r = idx >> 3, c8 = (idx & 7) << 3;
    u16x8 v = *(const u16x8*)&V[((size_t)b * 2048 + sy * 64 + r) * 1024 + ox * 64 + c8];
#pragma unroll
    for (int e = 0; e < 8; ++e) sV[r][c8 + e] = v[e];
  }
  __syncthreads();
#pragma unroll
  for (int it = 0; it < 2; ++it) {
    int idx = tid + it * 256;
    int ro = idx >> 3, cs = (idx & 7) << 3;
    u16x8 w;
#pragma unroll
    for (int e = 0; e < 8; ++e) w[e] = sV[cs + e][ro];
    *(u16x8*)&VT[((size_t)b * 1024 + ox * 64 + ro) * 2048 + sy * 64 + cs] = w;
  }
}

// ---------------------------------------------------------------------------
// Row softmax with causal mask + 1/sqrt(d) scale. Writes bf16 P in-place over
// the f32 scores buffer. Safe: reads complete before first barrier.
// ---------------------------------------------------------------------------
__global__ __launch_bounds__(256) void softmax_kernel(float* __restrict__ Sc) {
  const int row = blockIdx.x;  // b*2048 + q
  const int q = row & 2047;
  const int tid = threadIdx.x, lane = tid & 63, wave = tid >> 6;
  float* srow = Sc + (size_t)row * 2048;
  unsigned short* prow = (unsigned short*)srow;
  const int k0 = tid * 4, k1 = 1024 + tid * 4;
  f32x4 v0 = {}, v1 = {};
  if (k0 <= q) v0 = *(const f32x4*)(srow + k0);
  if (k1 <= q) v1 = *(const f32x4*)(srow + k1);
  float m = -3.0e38f;
#pragma unroll
  for (int e = 0; e < 4; ++e) {
    if (k0 + e <= q) m = fmaxf(m, v0[e]);
    if (k1 + e <= q) m = fmaxf(m, v1[e]);
  }
#pragma unroll
  for (int o = 32; o; o >>= 1) m = fmaxf(m, __shfl_xor(m, o));
  __shared__ float redm[4], reds[4];
  if (lane == 0) redm[wave] = m;
  __syncthreads();
  m = fmaxf(fmaxf(redm[0], redm[1]), fmaxf(redm[2], redm[3]));
  const float scale = 0.03125f;  // 1/sqrt(1024)
  float p[8];
  float s = 0.f;
#pragma unroll
  for (int e = 0; e < 4; ++e) {
    p[e] = (k0 + e <= q) ? __expf((v0[e] - m) * scale) : 0.f;
    p[4 + e] = (k1 + e <= q) ? __expf((v1[e] - m) * scale) : 0.f;
    s += p[e] + p[4 + e];
  }
#pragma unroll
  for (int o = 32; o; o >>= 1) s += __shfl_xor(s, o);
  if (lane == 0) reds[wave] = s;
  __syncthreads();
  s = reds[0] + reds[1] + reds[2] + reds[3];
  const float inv = 1.0f / s;
  u16x4 o0, o1;
#pragma unroll
  for (int e = 0; e < 4; ++e) {
    o0[e] = f2bf(p[e] * inv);
    o1[e] = f2bf(p[4 + e] * inv);
  }
  *(u16x4*)&prow[k0] = o0;
  *(u16x4*)&prow[k1] = o1;
}

// ---------------------------------------------------------------------------
extern "C" void kernel_launch(void* const* d_in, const int* in_sizes, int n_in,
                              void* d_out, int out_size, void* d_ws, size_t ws_size,
                              hipStream_t stream) {
  const float* Xk = (const float*)d_in[0];
  const float* Xv = (const float*)d_in[1];
  const float* Xq = (const float*)d_in[2];
  const float* Wk = (const float*)d_in[3];
  const float* Wv = (const float*)d_in[4];
  const float* Wq = (const float*)d_in[5];
  float* out = (float*)d_out;

  char* ws = (char*)d_ws;
  size_t off = 0;
  auto walloc = [&](size_t bytes) {
    void* p = ws + off;
    off += (bytes + 255) & ~(size_t)255;
    return p;
  };
  const size_t XSZ = 8192ull * 1024;  // elements per [8192x1024] matrix
  // X region (dead after projections): z order K=0, Q=1, V=2 for hi; K,Q for lo.
  unsigned short* Xh = (unsigned short*)walloc(3 * XSZ * 2);  // 48 MiB
  unsigned short* Xl = (unsigned short*)walloc(2 * XSZ * 2);  // 32 MiB (ends 80 MiB)
  unsigned short* WThi = (unsigned short*)walloc(3ull * 1024 * 1024 * 2);
  unsigned short* WTlo = (unsigned short*)walloc(3ull * 1024 * 1024 * 2);
  unsigned short* KQhi = (unsigned short*)walloc(2 * XSZ * 2);  // [Khi | Qhi]
  unsigned short* KQlo = (unsigned short*)walloc(2 * XSZ * 2);  // [Klo | Qlo]
  unsigned short* Vhi = (unsigned short*)walloc(XSZ * 2);
  // Aliases into the dead X region (written only after all projs complete):
  float* Sc = (float*)(ws + 0);                              // 64 MiB
  unsigned short* VT = (unsigned short*)(ws + 67108864ull);  // 16 MiB, ends 80 MiB

  convert_w_kernel<<<dim3(16, 16, 3), 256, 0, stream>>>(Wk, Wq, Wv, WThi, WTlo);
  convert_x_kernel<<<dim3(4096, 1, 3), 256, 0, stream>>>(Xk, Xq, Xv, Xh, Xl);

  // Fused K+Q projections (3-term, hi+lo out), batched over z: 0=K, 1=Q.
  gemm3_kernel<3, 1, false, false><<<dim3(8, 64, 2), 256, 0, stream>>>(
      Xh, Xl, WThi, WTlo, 1024, 1024, 1024, nullptr, KQhi, KQlo, 1024,
      XSZ, (size_t)1024 * 1024, XSZ);
  // V projection (plain bf16 1-term; hi out)
  gemm3_kernel<1, 2, false, false><<<dim3(8, 64, 1), 256, 0, stream>>>(
      Xh + 2 * XSZ, nullptr, WThi + 2u * 1048576u, nullptr,
      1024, 1024, 1024, nullptr, Vhi, nullptr, 1024, 0, 0, 0);

  transpose_v_kernel<<<dim3(16, 32, 4), 256, 0, stream>>>(Vhi, VT);

  // scores = Q.K^T (raw), packed lower-triangle tile grid, f32 out
  gemm3_kernel<3, 0, true, false><<<dim3(136, 1, 4), 256, 0, stream>>>(
      KQhi + XSZ, KQlo + XSZ, KQhi, KQlo, 1024, 1024, 1024, Sc, nullptr,
      nullptr, 2048, (size_t)2048 * 1024, (size_t)2048 * 1024,
      (size_t)2048 * 2048);

  softmax_kernel<<<dim3(8192), 256, 0, stream>>>(Sc);

  // out = P.V (P bf16 pitch 4096, VT K-major), K-loop stops at diagonal
  gemm3_kernel<1, 0, false, true><<<dim3(8, 16, 4), 256, 0, stream>>>(
      (const unsigned short*)Sc, nullptr, VT, nullptr, 4096, 2048, 2048,
      out, nullptr, nullptr, 1024, (size_t)2048 * 4096, (size_t)1024 * 2048,
      (size_t)2048 * 1024);
}

// Round 5
// 281.317 us; speedup vs baseline: 1.2401x; 1.2401x over previous
//
#include <hip/hip_runtime.h>
#include <math.h>

using f32x4  = __attribute__((ext_vector_type(4))) float;
using bf16x8 = __attribute__((ext_vector_type(8))) short;
using u16x8  = __attribute__((ext_vector_type(8))) unsigned short;
using u16x4  = __attribute__((ext_vector_type(4))) unsigned short;

static __device__ __forceinline__ unsigned short f2bf(float f) {
  unsigned int u = __builtin_bit_cast(unsigned int, f);
  u += 0x7FFFu + ((u >> 16) & 1u);
  return (unsigned short)(u >> 16);
}
static __device__ __forceinline__ float bf2f(unsigned short h) {
  unsigned int u = ((unsigned int)h) << 16;
  return __builtin_bit_cast(float, u);
}

// async global->LDS, 16B per lane. LDS dest is wave-uniform base; HW appends
// lane*16.
static __device__ __forceinline__ void gll16(const void* g, void* l) {
  using GPtr = const unsigned int __attribute__((address_space(1)))*;
  using LPtr = unsigned int __attribute__((address_space(3)))*;
  __builtin_amdgcn_global_load_lds((GPtr)(unsigned long long)g,
                                   (LPtr)(unsigned)(unsigned long long)l,
                                   16, 0, 0);
}

// Stage one [128][64] bf16 tile with XOR-swizzled layout:
// LDS[row][slot] (slot = 16B unit) holds global column-slot (slot ^ (row&7)).
// Linear LDS dest + pre-swizzled global source column (rule #21).
// Wave w stages rows [32w, 32w+32).
static __device__ __forceinline__ void stage64(unsigned short* sdst,
                                               const unsigned short* g,
                                               size_t ld, int k0, int wave,
                                               int lane) {
  const int r = lane >> 3;                  // 0..7 row within octet
  const int c8 = lane & 7;                  // dest 16B slot 0..7
  const int scol = (c8 ^ r) << 3;           // pre-swizzled source column (elems)
#pragma unroll
  for (int i = 0; i < 4; ++i) {
    const unsigned short* gp = g + (size_t)(wave * 32 + i * 8 + r) * ld + (k0 + scol);
    unsigned short* lp = sdst + wave * 2048 + i * 512;  // wave-uniform
    gll16(gp, lp);
  }
}

// Swizzled fragment read: row-major [128][64], element (row, kko..kko+7).
static __device__ __forceinline__ bf16x8 frag_ld(const unsigned short* s,
                                                 int row, int kko) {
  return *(const bf16x8*)&s[row * 64 + (kko ^ ((row & 7) << 3))];
}

// ---------------------------------------------------------------------------
// Elementwise split: W [1024x1024] f32 -> Wh/Wl bf16 (ORIGINAL layout).
// z: 0 = Wk, 1 = Wq.
// ---------------------------------------------------------------------------
__global__ __launch_bounds__(256) void split_w_kernel(
    const float* __restrict__ Wk, const float* __restrict__ Wq,
    unsigned short* __restrict__ Wkh, unsigned short* __restrict__ Wkl,
    unsigned short* __restrict__ Wqh, unsigned short* __restrict__ Wql) {
  const int z = blockIdx.z;
  const float* W = (z == 0) ? Wk : Wq;
  unsigned short* H = (z == 0) ? Wkh : Wqh;
  unsigned short* L = (z == 0) ? Wkl : Wql;
  const size_t base = ((size_t)blockIdx.x * 256 + threadIdx.x) * 8;
  float av[8];
  *(f32x4*)&av[0] = *(const f32x4*)&W[base];
  *(f32x4*)&av[4] = *(const f32x4*)&W[base + 4];
  u16x8 h, l;
#pragma unroll
  for (int e = 0; e < 8; ++e) {
    unsigned short hh = f2bf(av[e]);
    h[e] = hh;
    l[e] = f2bf(av[e] - bf2f(hh));
  }
  *(u16x8*)&H[base] = h;
  *(u16x8*)&L[base] = l;
}

// ---------------------------------------------------------------------------
// Wv [1024 i][1024 o] f32 -> WvT [1024 o][1024 i] bf16 hi (transposed)
// ---------------------------------------------------------------------------
__global__ __launch_bounds__(256) void convert_wv_kernel(
    const float* __restrict__ Wv, unsigned short* __restrict__ WvT) {
  __shared__ float sW[64][65];
  const int ti = blockIdx.x * 64;
  const int tj = blockIdx.y * 64;
  const int tid = threadIdx.x;
#pragma unroll
  for (int it = 0; it < 4; ++it) {
    int idx = tid + it * 256;
    int r = idx >> 4, c = (idx & 15) << 2;
    f32x4 v = *(const f32x4*)&Wv[(size_t)(ti + r) * 1024 + tj + c];
    sW[r][c] = v[0]; sW[r][c + 1] = v[1]; sW[r][c + 2] = v[2]; sW[r][c + 3] = v[3];
  }
  __syncthreads();
#pragma unroll
  for (int it = 0; it < 4; ++it) {
    int idx = tid + it * 256;
    int ro = idx >> 4, ci = (idx & 15) << 2;
    u16x4 h;
#pragma unroll
    for (int e = 0; e < 4; ++e) h[e] = f2bf(sW[ci + e][ro]);
    *(u16x4*)&WvT[(size_t)(tj + ro) * 1024 + ti + ci] = h;
  }
}

// ---------------------------------------------------------------------------
// X [8192 x 1024] f32 -> Xh (+Xl for z<2) bf16, same layout.
// z: 0 = keys, 1 = queries, 2 = values.
// ---------------------------------------------------------------------------
__global__ __launch_bounds__(256) void convert_x_kernel(
    const float* __restrict__ Xk, const float* __restrict__ Xq,
    const float* __restrict__ Xv, unsigned short* __restrict__ Xkh,
    unsigned short* __restrict__ Xkl, unsigned short* __restrict__ Xqh,
    unsigned short* __restrict__ Xql, unsigned short* __restrict__ Xvh) {
  const int z = blockIdx.z;
  const float* X = (z == 0) ? Xk : (z == 1) ? Xq : Xv;
  unsigned short* H = (z == 0) ? Xkh : (z == 1) ? Xqh : Xvh;
  unsigned short* L = (z == 0) ? Xkl : Xql;
  const size_t base = ((size_t)blockIdx.x * 256 + threadIdx.x) * 8;
  float av[8];
  *(f32x4*)&av[0] = *(const f32x4*)&X[base];
  *(f32x4*)&av[4] = *(const f32x4*)&X[base + 4];
  u16x8 h, l;
#pragma unroll
  for (int e = 0; e < 8; ++e) {
    unsigned short hh = f2bf(av[e]);
    h[e] = hh;
    l[e] = f2bf(av[e] - bf2f(hh));
  }
  *(u16x8*)&H[base] = h;
  if (z < 2) *(u16x8*)&L[base] = l;
}

// ---------------------------------------------------------------------------
// Unified split-bf16 GEMM (round-3 validated): 128x128 tile, BK=64, 4 waves,
// global_load_lds staging into XOR-swizzled [128][64] LDS tiles, 2 barriers
// per K-step. C = A * B^T, A rows = out rows, B rows = out cols, K-major.
// NTERMS: 3 = AhBh+AhBl+AlBh ; 2 = AhBh+AhBl ; 1 = AhBh.
// EPI: 0 = f32 C ; 1 = bf16 hi+lo ; 2 = bf16 hi.
// PACKED: blockIdx.x is a packed lower-triangle tile index.
// PVK: K-loop ends at (bm+1)*128.
// Note: abatch/bbatch also serve as a K-offset for split-K (z batches).
// ---------------------------------------------------------------------------
template <int NTERMS, int EPI, bool PACKED, bool PVK>
__global__ __launch_bounds__(256, 2) void gemm3_kernel(
    const unsigned short* __restrict__ Ah, const unsigned short* __restrict__ Al,
    const unsigned short* __restrict__ Bh, const unsigned short* __restrict__ Bl,
    size_t lda, size_t ldb, int K,
    float* __restrict__ Cf, unsigned short* __restrict__ Ch,
    unsigned short* __restrict__ Cl, size_t ldc,
    size_t abatch, size_t bbatch, size_t cbatch) {
  constexpr int NTILES = (NTERMS == 3) ? 4 : (NTERMS == 2) ? 3 : 2;
  __shared__ unsigned short smem[NTILES * 8192];
  int bm, bn;
  if constexpr (PACKED) {
    const int t = blockIdx.x;
    bm = (int)((sqrtf(8.f * (float)t + 1.f) - 1.f) * 0.5f);
    while ((bm + 1) * (bm + 2) / 2 <= t) ++bm;
    while (bm * (bm + 1) / 2 > t) --bm;
    bn = t - bm * (bm + 1) / 2;
  } else {
    bn = blockIdx.x;
    bm = blockIdx.y;
  }
  const int b = blockIdx.z;
  const int tid = threadIdx.x, lane = tid & 63, wave = tid >> 6;
  unsigned short* sAh = smem;
  unsigned short* sBh = smem + 8192;
  unsigned short* sBl = smem + 16384;  // NTERMS >= 2
  unsigned short* sAl = smem + 24576;  // NTERMS == 3
  const unsigned short* gA = Ah + abatch * b + (size_t)(bm * 128) * lda;
  const unsigned short* gB = Bh + bbatch * b + (size_t)(bn * 128) * ldb;
  const unsigned short* gAl2 =
      (NTERMS == 3) ? Al + abatch * b + (size_t)(bm * 128) * lda : nullptr;
  const unsigned short* gBl2 =
      (NTERMS >= 2) ? Bl + bbatch * b + (size_t)(bn * 128) * ldb : nullptr;
  const int kend = PVK ? (bm + 1) * 128 : K;
  f32x4 acc[4][4] = {};
  const int wr = (wave >> 1) << 6, wc = (wave & 1) << 6;
  const int frow = lane & 15, koff = (lane >> 4) << 3;
  for (int k0 = 0; k0 < kend; k0 += 64) {
    __syncthreads();  // all waves done reading previous tile
    stage64(sAh, gA, lda, k0, wave, lane);
    stage64(sBh, gB, ldb, k0, wave, lane);
    if constexpr (NTERMS >= 2) stage64(sBl, gBl2, ldb, k0, wave, lane);
    if constexpr (NTERMS == 3) stage64(sAl, gAl2, lda, k0, wave, lane);
    __syncthreads();  // staging complete
#pragma unroll
    for (int kk = 0; kk < 64; kk += 32) {
      const int kko = kk + koff;
      bf16x8 fBh[4], fBl[4];
#pragma unroll
      for (int j = 0; j < 4; ++j) {
        fBh[j] = frag_ld(sBh, wc + j * 16 + frow, kko);
        if constexpr (NTERMS >= 2) fBl[j] = frag_ld(sBl, wc + j * 16 + frow, kko);
      }
#pragma unroll
      for (int i = 0; i < 4; ++i) {
        const bf16x8 ah = frag_ld(sAh, wr + i * 16 + frow, kko);
        bf16x8 al = {};
        if constexpr (NTERMS == 3) al = frag_ld(sAl, wr + i * 16 + frow, kko);
#pragma unroll
        for (int j = 0; j < 4; ++j) {
          acc[i][j] = __builtin_amdgcn_mfma_f32_16x16x32_bf16(ah, fBh[j], acc[i][j], 0, 0, 0);
          if constexpr (NTERMS >= 2)
            acc[i][j] = __builtin_amdgcn_mfma_f32_16x16x32_bf16(ah, fBl[j], acc[i][j], 0, 0, 0);
          if constexpr (NTERMS == 3)
            acc[i][j] = __builtin_amdgcn_mfma_f32_16x16x32_bf16(al, fBh[j], acc[i][j], 0, 0, 0);
        }
      }
    }
  }
  const int erow = bm * 128 + wr + ((lane >> 4) << 2);
  const int ecol = bn * 128 + wc + frow;
  if constexpr (EPI == 0) {
    float* C = Cf + cbatch * b;
#pragma unroll
    for (int i = 0; i < 4; ++i)
#pragma unroll
      for (int j = 0; j < 4; ++j)
#pragma unroll
        for (int e = 0; e < 4; ++e)
          C[(size_t)(erow + i * 16 + e) * ldc + (ecol + j * 16)] = acc[i][j][e];
  } else {
    unsigned short* Cho = Ch + cbatch * b;
    unsigned short* Clo = (EPI == 1) ? Cl + cbatch * b : nullptr;
#pragma unroll
    for (int i = 0; i < 4; ++i)
#pragma unroll
      for (int j = 0; j < 4; ++j)
#pragma unroll
        for (int e = 0; e < 4; ++e) {
          size_t off = (size_t)(erow + i * 16 + e) * ldc + (ecol + j * 16);
          float v = acc[i][j][e];
          unsigned short hh = f2bf(v);
          Cho[off] = hh;
          if constexpr (EPI == 1) Clo[off] = f2bf(v - bf2f(hh));
        }
  }
}

// ---------------------------------------------------------------------------
// Sum 4 split-K partials of MT (f32) -> MThi/MTlo bf16 split. [1024x1024]
// ---------------------------------------------------------------------------
__global__ __launch_bounds__(256) void reduce_mt_kernel(
    const float* __restrict__ P, unsigned short* __restrict__ H,
    unsigned short* __restrict__ L) {
  const size_t base = ((size_t)blockIdx.x * 256 + threadIdx.x) * 4;
  f32x4 s = *(const f32x4*)&P[base];
#pragma unroll
  for (int z = 1; z < 4; ++z) {
    f32x4 v = *(const f32x4*)&P[(size_t)z * 1048576 + base];
    s[0] += v[0]; s[1] += v[1]; s[2] += v[2]; s[3] += v[3];
  }
  u16x4 h, l;
#pragma unroll
  for (int e = 0; e < 4; ++e) {
    unsigned short hh = f2bf(s[e]);
    h[e] = hh;
    l[e] = f2bf(s[e] - bf2f(hh));
  }
  *(u16x4*)&H[base] = h;
  *(u16x4*)&L[base] = l;
}

// ---------------------------------------------------------------------------
// V [b][2048 s][1024 o] bf16 -> VT [b][1024 o][2048 s] bf16
// ---------------------------------------------------------------------------
__global__ __launch_bounds__(256) void transpose_v_kernel(
    const unsigned short* __restrict__ V, unsigned short* __restrict__ VT) {
  __shared__ unsigned short sV[64][72];
  const int ox = blockIdx.x, sy = blockIdx.y, b = blockIdx.z;
  const int tid = threadIdx.x;
#pragma unroll
  for (int it = 0; it < 2; ++it) {
    int idx = tid + it * 256;
    int r = idx >> 3, c8 = (idx & 7) << 3;
    u16x8 v = *(const u16x8*)&V[((size_t)b * 2048 + sy * 64 + r) * 1024 + ox * 64 + c8];
#pragma unroll
    for (int e = 0; e < 8; ++e) sV[r][c8 + e] = v[e];
  }
  __syncthreads();
#pragma unroll
  for (int it = 0; it < 2; ++it) {
    int idx = tid + it * 256;
    int ro = idx >> 3, cs = (idx & 7) << 3;
    u16x8 w;
#pragma unroll
    for (int e = 0; e < 8; ++e) w[e] = sV[cs + e][ro];
    *(u16x8*)&VT[((size_t)b * 1024 + ox * 64 + ro) * 2048 + sy * 64 + cs] = w;
  }
}

// ---------------------------------------------------------------------------
// Row softmax with causal mask + 1/sqrt(d) scale. Writes bf16 P in-place over
// the f32 scores buffer. Safe: reads complete before first barrier.
// ---------------------------------------------------------------------------
__global__ __launch_bounds__(256) void softmax_kernel(float* __restrict__ Sc) {
  const int row = blockIdx.x;  // b*2048 + q
  const int q = row & 2047;
  const int tid = threadIdx.x, lane = tid & 63, wave = tid >> 6;
  float* srow = Sc + (size_t)row * 2048;
  unsigned short* prow = (unsigned short*)srow;
  const int k0 = tid * 4, k1 = 1024 + tid * 4;
  f32x4 v0 = {}, v1 = {};
  if (k0 <= q) v0 = *(const f32x4*)(srow + k0);
  if (k1 <= q) v1 = *(const f32x4*)(srow + k1);
  float m = -3.0e38f;
#pragma unroll
  for (int e = 0; e < 4; ++e) {
    if (k0 + e <= q) m = fmaxf(m, v0[e]);
    if (k1 + e <= q) m = fmaxf(m, v1[e]);
  }
#pragma unroll
  for (int o = 32; o; o >>= 1) m = fmaxf(m, __shfl_xor(m, o));
  __shared__ float redm[4], reds[4];
  if (lane == 0) redm[wave] = m;
  __syncthreads();
  m = fmaxf(fmaxf(redm[0], redm[1]), fmaxf(redm[2], redm[3]));
  const float scale = 0.03125f;  // 1/sqrt(1024)
  float p[8];
  float s = 0.f;
#pragma unroll
  for (int e = 0; e < 4; ++e) {
    p[e] = (k0 + e <= q) ? __expf((v0[e] - m) * scale) : 0.f;
    p[4 + e] = (k1 + e <= q) ? __expf((v1[e] - m) * scale) : 0.f;
    s += p[e] + p[4 + e];
  }
#pragma unroll
  for (int o = 32; o; o >>= 1) s += __shfl_xor(s, o);
  if (lane == 0) reds[wave] = s;
  __syncthreads();
  s = reds[0] + reds[1] + reds[2] + reds[3];
  const float inv = 1.0f / s;
  u16x4 o0, o1;
#pragma unroll
  for (int e = 0; e < 4; ++e) {
    o0[e] = f2bf(p[e] * inv);
    o1[e] = f2bf(p[4 + e] * inv);
  }
  *(u16x4*)&prow[k0] = o0;
  *(u16x4*)&prow[k1] = o1;
}

// ---------------------------------------------------------------------------
extern "C" void kernel_launch(void* const* d_in, const int* in_sizes, int n_in,
                              void* d_out, int out_size, void* d_ws, size_t ws_size,
                              hipStream_t stream) {
  const float* Xk = (const float*)d_in[0];
  const float* Xv = (const float*)d_in[1];
  const float* Xq = (const float*)d_in[2];
  const float* Wk = (const float*)d_in[3];
  const float* Wv = (const float*)d_in[4];
  const float* Wq = (const float*)d_in[5];
  float* out = (float*)d_out;

  char* ws = (char*)d_ws;
  const size_t MB = 1024ull * 1024;
  // Liveness-planned layout (174 MB total). [0,64MB) is dead by scores time
  // and is reused for Sc.
  unsigned short* Xqh   = (unsigned short*)(ws + 0);          // 16MB, dead after T
  unsigned short* Xvh   = (unsigned short*)(ws + 16 * MB);    // 16MB, dead after Vproj
  unsigned short* Xql   = (unsigned short*)(ws + 32 * MB);    // 16MB, dead after T
  unsigned short* Wkh   = (unsigned short*)(ws + 48 * MB);    // 2MB, dead after M
  unsigned short* Wkl   = (unsigned short*)(ws + 50 * MB);
  unsigned short* Wqh   = (unsigned short*)(ws + 52 * MB);
  unsigned short* Wql   = (unsigned short*)(ws + 54 * MB);
  unsigned short* MThi  = (unsigned short*)(ws + 56 * MB);    // 2MB, dead after T
  unsigned short* MTlo  = (unsigned short*)(ws + 58 * MB);
  unsigned short* Vhi   = (unsigned short*)(ws + 60 * MB);    // 16MB, dead after transpose
  unsigned short* Xkh   = (unsigned short*)(ws + 76 * MB);    // 16MB, live thru scores
  unsigned short* Xkl   = (unsigned short*)(ws + 92 * MB);    // 16MB
  unsigned short* Thi   = (unsigned short*)(ws + 108 * MB);   // 16MB, live thru scores
  unsigned short* Tlo   = (unsigned short*)(ws + 124 * MB);   // 16MB
  unsigned short* VT    = (unsigned short*)(ws + 140 * MB);   // 16MB, live thru PV
  unsigned short* WvT   = (unsigned short*)(ws + 156 * MB);   // 2MB, dead after Vproj
  float*          MTpart= (float*)(ws + 158 * MB);            // 16MB f32, dead after reduce
  float*          Sc    = (float*)(ws + 0);                   // 64MB alias over dead region

  // --- precision prep ---
  split_w_kernel<<<dim3(512, 1, 2), 256, 0, stream>>>(Wk, Wq, Wkh, Wkl, Wqh, Wql);
  convert_wv_kernel<<<dim3(16, 16), 256, 0, stream>>>(Wv, WvT);
  convert_x_kernel<<<dim3(4096, 1, 3), 256, 0, stream>>>(Xk, Xq, Xv, Xkh, Xkl,
                                                         Xqh, Xql, Xvh);

  // --- M^T = Wk . Wq^T  (MT[j][i] = sum_o Wk[j,o] Wq[i,o]), split-K over 4
  // 256-wide K-slices (abatch/bbatch act as the K offset), f32 partials ---
  gemm3_kernel<3, 0, false, false><<<dim3(8, 8, 4), 256, 0, stream>>>(
      Wkh, Wkl, Wqh, Wql, 1024, 1024, 256, MTpart, nullptr, nullptr, 1024,
      256, 256, (size_t)1024 * 1024);
  reduce_mt_kernel<<<dim3(1024), 256, 0, stream>>>(MTpart, MThi, MTlo);

  // --- T = Xq . MT^T  (T[s,j] = sum_i Xq[s,i] M[i,j]), 3-term, hi+lo out ---
  gemm3_kernel<3, 1, false, false><<<dim3(8, 64, 1), 256, 0, stream>>>(
      Xqh, Xql, MThi, MTlo, 1024, 1024, 1024, nullptr, Thi, Tlo, 1024, 0, 0, 0);

  // --- V = Xv . Wv (plain bf16 1-term; hi out) ---
  gemm3_kernel<1, 2, false, false><<<dim3(8, 64, 1), 256, 0, stream>>>(
      Xvh, nullptr, WvT, nullptr, 1024, 1024, 1024, nullptr, Vhi, nullptr,
      1024, 0, 0, 0);

  transpose_v_kernel<<<dim3(16, 32, 4), 256, 0, stream>>>(Vhi, VT);

  // --- scores = T . Xk^T (raw), packed lower-triangle tiles, f32 out ---
  gemm3_kernel<3, 0, true, false><<<dim3(136, 1, 4), 256, 0, stream>>>(
      Thi, Tlo, Xkh, Xkl, 1024, 1024, 1024, Sc, nullptr, nullptr, 2048,
      (size_t)2048 * 1024, (size_t)2048 * 1024, (size_t)2048 * 2048);

  softmax_kernel<<<dim3(8192), 256, 0, stream>>>(Sc);

  // --- out = P . V (P bf16 pitch 4096, VT K-major), K stops at diagonal ---
  gemm3_kernel<1, 0, false, true><<<dim3(8, 16, 4), 256, 0, stream>>>(
      (const unsigned short*)Sc, nullptr, VT, nullptr, 4096, 2048, 2048,
      out, nullptr, nullptr, 1024, (size_t)2048 * 4096, (size_t)1024 * 2048,
      (size_t)2048 * 1024);
}

// Round 6
// 259.915 us; speedup vs baseline: 1.3422x; 1.0823x over previous
//
#include <hip/hip_runtime.h>
#include <math.h>

using f32x4  = __attribute__((ext_vector_type(4))) float;
using bf16x8 = __attribute__((ext_vector_type(8))) short;
using u16x8  = __attribute__((ext_vector_type(8))) unsigned short;
using u16x4  = __attribute__((ext_vector_type(4))) unsigned short;

static __device__ __forceinline__ unsigned short f2bf(float f) {
  unsigned int u = __builtin_bit_cast(unsigned int, f);
  u += 0x7FFFu + ((u >> 16) & 1u);
  return (unsigned short)(u >> 16);
}
static __device__ __forceinline__ float bf2f(unsigned short h) {
  unsigned int u = ((unsigned int)h) << 16;
  return __builtin_bit_cast(float, u);
}

// async global->LDS, 16B per lane. LDS dest is wave-uniform base; HW appends
// lane*16.
static __device__ __forceinline__ void gll16(const void* g, void* l) {
  using GPtr = const unsigned int __attribute__((address_space(1)))*;
  using LPtr = unsigned int __attribute__((address_space(3)))*;
  __builtin_amdgcn_global_load_lds((GPtr)(unsigned long long)g,
                                   (LPtr)(unsigned)(unsigned long long)l,
                                   16, 0, 0);
}

// Stage one [128][BK] bf16 tile, XOR-swizzled via pre-swizzled global source
// column + linear LDS dest (rule #21). Wave w stages rows [32w, 32w+32).
// BK=64: swizzle slot^row over 8 slots; BK=32: slot^(row&3) over 4 slots.
template <int BK>
static __device__ __forceinline__ void stageT(unsigned short* sdst,
                                              const unsigned short* g,
                                              size_t ld, int k0, int wave,
                                              int lane) {
  if constexpr (BK == 64) {
    const int r = lane >> 3, c8 = lane & 7;
    const int scol = (c8 ^ r) << 3;
#pragma unroll
    for (int i = 0; i < 4; ++i)
      gll16(g + (size_t)(wave * 32 + i * 8 + r) * ld + (k0 + scol),
            sdst + wave * 2048 + i * 512);
  } else {
    const int r = lane >> 2, c4 = lane & 3;
    const int scol = (c4 ^ (r & 3)) << 3;
#pragma unroll
    for (int i = 0; i < 2; ++i)
      gll16(g + (size_t)(wave * 32 + i * 16 + r) * ld + (k0 + scol),
            sdst + wave * 1024 + i * 512);
  }
}

// Swizzled fragment read: row-major [128][BK], element (row, kko..kko+7).
template <int BK>
static __device__ __forceinline__ bf16x8 fragT(const unsigned short* s,
                                               int row, int kko) {
  if constexpr (BK == 64)
    return *(const bf16x8*)&s[row * 64 + (kko ^ ((row & 7) << 3))];
  else
    return *(const bf16x8*)&s[row * 32 + (kko ^ ((row & 3) << 3))];
}

// ---------------------------------------------------------------------------
// Elementwise split: W [1024x1024] f32 -> Wh/Wl bf16 (ORIGINAL layout).
// z: 0 = Wk, 1 = Wq.
// ---------------------------------------------------------------------------
__global__ __launch_bounds__(256) void split_w_kernel(
    const float* __restrict__ Wk, const float* __restrict__ Wq,
    unsigned short* __restrict__ Wkh, unsigned short* __restrict__ Wkl,
    unsigned short* __restrict__ Wqh, unsigned short* __restrict__ Wql) {
  const int z = blockIdx.z;
  const float* W = (z == 0) ? Wk : Wq;
  unsigned short* H = (z == 0) ? Wkh : Wqh;
  unsigned short* L = (z == 0) ? Wkl : Wql;
  const size_t base = ((size_t)blockIdx.x * 256 + threadIdx.x) * 8;
  float av[8];
  *(f32x4*)&av[0] = *(const f32x4*)&W[base];
  *(f32x4*)&av[4] = *(const f32x4*)&W[base + 4];
  u16x8 h, l;
#pragma unroll
  for (int e = 0; e < 8; ++e) {
    unsigned short hh = f2bf(av[e]);
    h[e] = hh;
    l[e] = f2bf(av[e] - bf2f(hh));
  }
  *(u16x8*)&H[base] = h;
  *(u16x8*)&L[base] = l;
}

// ---------------------------------------------------------------------------
// Wv [1024 i][1024 o] f32 -> WvT [1024 o][1024 i] bf16 hi (transposed)
// ---------------------------------------------------------------------------
__global__ __launch_bounds__(256) void convert_wv_kernel(
    const float* __restrict__ Wv, unsigned short* __restrict__ WvT) {
  __shared__ float sW[64][65];
  const int ti = blockIdx.x * 64;
  const int tj = blockIdx.y * 64;
  const int tid = threadIdx.x;
#pragma unroll
  for (int it = 0; it < 4; ++it) {
    int idx = tid + it * 256;
    int r = idx >> 4, c = (idx & 15) << 2;
    f32x4 v = *(const f32x4*)&Wv[(size_t)(ti + r) * 1024 + tj + c];
    sW[r][c] = v[0]; sW[r][c + 1] = v[1]; sW[r][c + 2] = v[2]; sW[r][c + 3] = v[3];
  }
  __syncthreads();
#pragma unroll
  for (int it = 0; it < 4; ++it) {
    int idx = tid + it * 256;
    int ro = idx >> 4, ci = (idx & 15) << 2;
    u16x4 h;
#pragma unroll
    for (int e = 0; e < 4; ++e) h[e] = f2bf(sW[ci + e][ro]);
    *(u16x4*)&WvT[(size_t)(tj + ro) * 1024 + ti + ci] = h;
  }
}

// ---------------------------------------------------------------------------
// X [8192 x 1024] f32 -> Xh (+Xl for z<2) bf16, same layout.
// z: 0 = keys, 1 = queries, 2 = values.
// ---------------------------------------------------------------------------
__global__ __launch_bounds__(256) void convert_x_kernel(
    const float* __restrict__ Xk, const float* __restrict__ Xq,
    const float* __restrict__ Xv, unsigned short* __restrict__ Xkh,
    unsigned short* __restrict__ Xkl, unsigned short* __restrict__ Xqh,
    unsigned short* __restrict__ Xql, unsigned short* __restrict__ Xvh) {
  const int z = blockIdx.z;
  const float* X = (z == 0) ? Xk : (z == 1) ? Xq : Xv;
  unsigned short* H = (z == 0) ? Xkh : (z == 1) ? Xqh : Xvh;
  unsigned short* L = (z == 0) ? Xkl : Xql;
  const size_t base = ((size_t)blockIdx.x * 256 + threadIdx.x) * 8;
  float av[8];
  *(f32x4*)&av[0] = *(const f32x4*)&X[base];
  *(f32x4*)&av[4] = *(const f32x4*)&X[base + 4];
  u16x8 h, l;
#pragma unroll
  for (int e = 0; e < 8; ++e) {
    unsigned short hh = f2bf(av[e]);
    h[e] = hh;
    l[e] = f2bf(av[e] - bf2f(hh));
  }
  *(u16x8*)&H[base] = h;
  if (z < 2) *(u16x8*)&L[base] = l;
}

// ---------------------------------------------------------------------------
// Unified split-bf16 GEMM with 2-phase double-buffered global_load_lds
// staging (catalog T3-minimum) + bijective XCD block swizzle (T1).
// 128x128 tile, 4 waves. NTERMS==3: BK=32, 4 tiles/buf; NTERMS==1: BK=64,
// 2 tiles/buf. LDS = 64KB either way (2 blocks/CU).
// Per step: issue next-tile stages -> compute current -> __syncthreads()
// (implicit vmcnt(0) drain lands AFTER compute, hiding stage latency).
// C = A * B^T, A rows = out rows, B rows = out cols, K-major.
// EPI: 0 = f32 C ; 1 = bf16 hi+lo ; 2 = bf16 hi.
// PACKED: lid%gx is a packed lower-triangle tile index.
// PVK: K-loop ends at (bm+1)*128.
// ---------------------------------------------------------------------------
template <int NTERMS, int EPI, bool PACKED, bool PVK>
__global__ __launch_bounds__(256, 2) void gemm_db_kernel(
    const unsigned short* __restrict__ Ah, const unsigned short* __restrict__ Al,
    const unsigned short* __restrict__ Bh, const unsigned short* __restrict__ Bl,
    size_t lda, size_t ldb, int K,
    float* __restrict__ Cf, unsigned short* __restrict__ Ch,
    unsigned short* __restrict__ Cl, size_t ldc,
    size_t abatch, size_t bbatch, size_t cbatch) {
  constexpr int BK = (NTERMS == 3) ? 32 : 64;
  constexpr int NTILES = (NTERMS == 3) ? 4 : 2;
  constexpr int TILE = 128 * BK;  // shorts per tile
  __shared__ unsigned short smem[2][NTILES * TILE];

  // Bijective XCD-chunked swizzle over the full linearized grid (m204).
  int lid = blockIdx.x + gridDim.x * (blockIdx.y + gridDim.y * blockIdx.z);
  {
    const int n = gridDim.x * gridDim.y * gridDim.z;
    const int q = n >> 3, r = n & 7, x = lid & 7, k = lid >> 3;
    lid = (x < r ? x * (q + 1) : r * (q + 1) + (x - r) * q) + k;
  }
  int bm, bn, b;
  if constexpr (PACKED) {
    const int t = lid % gridDim.x;
    b = lid / gridDim.x;
    bm = (int)((sqrtf(8.f * (float)t + 1.f) - 1.f) * 0.5f);
    while ((bm + 1) * (bm + 2) / 2 <= t) ++bm;
    while (bm * (bm + 1) / 2 > t) --bm;
    bn = t - bm * (bm + 1) / 2;
  } else {
    bn = lid % gridDim.x;
    const int tmp = lid / gridDim.x;
    bm = tmp % gridDim.y;
    b = tmp / gridDim.y;
  }
  const int tid = threadIdx.x, lane = tid & 63, wave = tid >> 6;
  const unsigned short* gA = Ah + abatch * b + (size_t)(bm * 128) * lda;
  const unsigned short* gB = Bh + bbatch * b + (size_t)(bn * 128) * ldb;
  const unsigned short* gAl2 =
      (NTERMS == 3) ? Al + abatch * b + (size_t)(bm * 128) * lda : nullptr;
  const unsigned short* gBl2 =
      (NTERMS == 3) ? Bl + bbatch * b + (size_t)(bn * 128) * ldb : nullptr;
  const int kend = PVK ? (bm + 1) * 128 : K;
  const int nsteps = kend / BK;
  f32x4 acc[4][4] = {};
  const int wr = (wave >> 1) << 6, wc = (wave & 1) << 6;
  const int frow = lane & 15, koff = (lane >> 4) << 3;

  auto stage_all = [&](unsigned short* buf, int k0) {
    stageT<BK>(buf, gA, lda, k0, wave, lane);
    stageT<BK>(buf + TILE, gB, ldb, k0, wave, lane);
    if constexpr (NTERMS == 3) {
      stageT<BK>(buf + 2 * TILE, gBl2, ldb, k0, wave, lane);
      stageT<BK>(buf + 3 * TILE, gAl2, lda, k0, wave, lane);
    }
  };

  stage_all(smem[0], 0);
  __syncthreads();  // implicit vmcnt(0): buf0 ready
  int cur = 0;
  for (int st = 0; st < nsteps; ++st) {
    if (st + 1 < nsteps) stage_all(smem[cur ^ 1], (st + 1) * BK);  // async
    const unsigned short* sA = smem[cur];
    const unsigned short* sB = smem[cur] + TILE;
    if constexpr (NTERMS == 3) {
      const unsigned short* sBl = smem[cur] + 2 * TILE;
      const unsigned short* sAl = smem[cur] + 3 * TILE;
      bf16x8 fBh[4], fBl[4];
#pragma unroll
      for (int j = 0; j < 4; ++j) {
        fBh[j] = fragT<BK>(sB, wc + j * 16 + frow, koff);
        fBl[j] = fragT<BK>(sBl, wc + j * 16 + frow, koff);
      }
#pragma unroll
      for (int i = 0; i < 4; ++i) {
        const bf16x8 ah = fragT<BK>(sA, wr + i * 16 + frow, koff);
        const bf16x8 al = fragT<BK>(sAl, wr + i * 16 + frow, koff);
#pragma unroll
        for (int j = 0; j < 4; ++j) {
          acc[i][j] = __builtin_amdgcn_mfma_f32_16x16x32_bf16(ah, fBh[j], acc[i][j], 0, 0, 0);
          acc[i][j] = __builtin_amdgcn_mfma_f32_16x16x32_bf16(ah, fBl[j], acc[i][j], 0, 0, 0);
          acc[i][j] = __builtin_amdgcn_mfma_f32_16x16x32_bf16(al, fBh[j], acc[i][j], 0, 0, 0);
        }
      }
    } else {
#pragma unroll
      for (int kk = 0; kk < 64; kk += 32) {
        const int kko = kk + koff;
        bf16x8 fBh[4];
#pragma unroll
        for (int j = 0; j < 4; ++j) fBh[j] = fragT<BK>(sB, wc + j * 16 + frow, kko);
#pragma unroll
        for (int i = 0; i < 4; ++i) {
          const bf16x8 ah = fragT<BK>(sA, wr + i * 16 + frow, kko);
#pragma unroll
          for (int j = 0; j < 4; ++j)
            acc[i][j] = __builtin_amdgcn_mfma_f32_16x16x32_bf16(ah, fBh[j], acc[i][j], 0, 0, 0);
        }
      }
    }
    __syncthreads();  // implicit vmcnt(0): next buffer staged, reads done
    cur ^= 1;
  }

  const int erow = bm * 128 + wr + ((lane >> 4) << 2);
  const int ecol = bn * 128 + wc + frow;
  if constexpr (EPI == 0) {
    float* C = Cf + cbatch * b;
#pragma unroll
    for (int i = 0; i < 4; ++i)
#pragma unroll
      for (int j = 0; j < 4; ++j)
#pragma unroll
        for (int e = 0; e < 4; ++e)
          C[(size_t)(erow + i * 16 + e) * ldc + (ecol + j * 16)] = acc[i][j][e];
  } else {
    unsigned short* Cho = Ch + cbatch * b;
    unsigned short* Clo = (EPI == 1) ? Cl + cbatch * b : nullptr;
#pragma unroll
    for (int i = 0; i < 4; ++i)
#pragma unroll
      for (int j = 0; j < 4; ++j)
#pragma unroll
        for (int e = 0; e < 4; ++e) {
          size_t off = (size_t)(erow + i * 16 + e) * ldc + (ecol + j * 16);
          float v = acc[i][j][e];
          unsigned short hh = f2bf(v);
          Cho[off] = hh;
          if constexpr (EPI == 1) Clo[off] = f2bf(v - bf2f(hh));
        }
  }
}

// ---------------------------------------------------------------------------
// Sum 4 split-K partials of MT (f32) -> MThi/MTlo bf16 split. [1024x1024]
// ---------------------------------------------------------------------------
__global__ __launch_bounds__(256) void reduce_mt_kernel(
    const float* __restrict__ P, unsigned short* __restrict__ H,
    unsigned short* __restrict__ L) {
  const size_t base = ((size_t)blockIdx.x * 256 + threadIdx.x) * 4;
  f32x4 s = *(const f32x4*)&P[base];
#pragma unroll
  for (int z = 1; z < 4; ++z) {
    f32x4 v = *(const f32x4*)&P[(size_t)z * 1048576 + base];
    s[0] += v[0]; s[1] += v[1]; s[2] += v[2]; s[3] += v[3];
  }
  u16x4 h, l;
#pragma unroll
  for (int e = 0; e < 4; ++e) {
    unsigned short hh = f2bf(s[e]);
    h[e] = hh;
    l[e] = f2bf(s[e] - bf2f(hh));
  }
  *(u16x4*)&H[base] = h;
  *(u16x4*)&L[base] = l;
}

// ---------------------------------------------------------------------------
// V [b][2048 s][1024 o] bf16 -> VT [b][1024 o][2048 s] bf16
// ---------------------------------------------------------------------------
__global__ __launch_bounds__(256) void transpose_v_kernel(
    const unsigned short* __restrict__ V, unsigned short* __restrict__ VT) {
  __shared__ unsigned short sV[64][72];
  const int ox = blockIdx.x, sy = blockIdx.y, b = blockIdx.z;
  const int tid = threadIdx.x;
#pragma unroll
  for (int it = 0; it < 2; ++it) {
    int idx = tid + it * 256;
    int r = idx >> 3, c8 = (idx & 7) << 3;
    u16x8 v = *(const u16x8*)&V[((size_t)b * 2048 + sy * 64 + r) * 1024 + ox * 64 + c8];
#pragma unroll
    for (int e = 0; e < 8; ++e) sV[r][c8 + e] = v[e];
  }
  __syncthreads();
#pragma unroll
  for (int it = 0; it < 2; ++it) {
    int idx = tid + it * 256;
    int ro = idx >> 3, cs = (idx & 7) << 3;
    u16x8 w;
#pragma unroll
    for (int e = 0; e < 8; ++e) w[e] = sV[cs + e][ro];
    *(u16x8*)&VT[((size_t)b * 1024 + ox * 64 + ro) * 2048 + sy * 64 + cs] = w;
  }
}

// ---------------------------------------------------------------------------
// Row softmax with causal mask + 1/sqrt(d) scale. Writes bf16 P in-place over
// the f32 scores buffer. Safe: reads complete before first barrier.
// ---------------------------------------------------------------------------
__global__ __launch_bounds__(256) void softmax_kernel(float* __restrict__ Sc) {
  const int row = blockIdx.x;  // b*2048 + q
  const int q = row & 2047;
  const int tid = threadIdx.x, lane = tid & 63, wave = tid >> 6;
  float* srow = Sc + (size_t)row * 2048;
  unsigned short* prow = (unsigned short*)srow;
  const int k0 = tid * 4, k1 = 1024 + tid * 4;
  f32x4 v0 = {}, v1 = {};
  if (k0 <= q) v0 = *(const f32x4*)(srow + k0);
  if (k1 <= q) v1 = *(const f32x4*)(srow + k1);
  float m = -3.0e38f;
#pragma unroll
  for (int e = 0; e < 4; ++e) {
    if (k0 + e <= q) m = fmaxf(m, v0[e]);
    if (k1 + e <= q) m = fmaxf(m, v1[e]);
  }
#pragma unroll
  for (int o = 32; o; o >>= 1) m = fmaxf(m, __shfl_xor(m, o));
  __shared__ float redm[4], reds[4];
  if (lane == 0) redm[wave] = m;
  __syncthreads();
  m = fmaxf(fmaxf(redm[0], redm[1]), fmaxf(redm[2], redm[3]));
  const float scale = 0.03125f;  // 1/sqrt(1024)
  float p[8];
  float s = 0.f;
#pragma unroll
  for (int e = 0; e < 4; ++e) {
    p[e] = (k0 + e <= q) ? __expf((v0[e] - m) * scale) : 0.f;
    p[4 + e] = (k1 + e <= q) ? __expf((v1[e] - m) * scale) : 0.f;
    s += p[e] + p[4 + e];
  }
#pragma unroll
  for (int o = 32; o; o >>= 1) s += __shfl_xor(s, o);
  if (lane == 0) reds[wave] = s;
  __syncthreads();
  s = reds[0] + reds[1] + reds[2] + reds[3];
  const float inv = 1.0f / s;
  u16x4 o0, o1;
#pragma unroll
  for (int e = 0; e < 4; ++e) {
    o0[e] = f2bf(p[e] * inv);
    o1[e] = f2bf(p[4 + e] * inv);
  }
  *(u16x4*)&prow[k0] = o0;
  *(u16x4*)&prow[k1] = o1;
}

// ---------------------------------------------------------------------------
extern "C" void kernel_launch(void* const* d_in, const int* in_sizes, int n_in,
                              void* d_out, int out_size, void* d_ws, size_t ws_size,
                              hipStream_t stream) {
  const float* Xk = (const float*)d_in[0];
  const float* Xv = (const float*)d_in[1];
  const float* Xq = (const float*)d_in[2];
  const float* Wk = (const float*)d_in[3];
  const float* Wv = (const float*)d_in[4];
  const float* Wq = (const float*)d_in[5];
  float* out = (float*)d_out;

  char* ws = (char*)d_ws;
  const size_t MB = 1024ull * 1024;
  // Liveness-planned layout (174 MB total). [0,64MB) is dead by scores time
  // and is reused for Sc.
  unsigned short* Xqh   = (unsigned short*)(ws + 0);          // 16MB, dead after T
  unsigned short* Xvh   = (unsigned short*)(ws + 16 * MB);    // 16MB, dead after Vproj
  unsigned short* Xql   = (unsigned short*)(ws + 32 * MB);    // 16MB, dead after T
  unsigned short* Wkh   = (unsigned short*)(ws + 48 * MB);    // 2MB, dead after M
  unsigned short* Wkl   = (unsigned short*)(ws + 50 * MB);
  unsigned short* Wqh   = (unsigned short*)(ws + 52 * MB);
  unsigned short* Wql   = (unsigned short*)(ws + 54 * MB);
  unsigned short* MThi  = (unsigned short*)(ws + 56 * MB);    // 2MB, dead after T
  unsigned short* MTlo  = (unsigned short*)(ws + 58 * MB);
  unsigned short* Vhi   = (unsigned short*)(ws + 60 * MB);    // 16MB, dead after transpose
  unsigned short* Xkh   = (unsigned short*)(ws + 76 * MB);    // 16MB, live thru scores
  unsigned short* Xkl   = (unsigned short*)(ws + 92 * MB);    // 16MB
  unsigned short* Thi   = (unsigned short*)(ws + 108 * MB);   // 16MB, live thru scores
  unsigned short* Tlo   = (unsigned short*)(ws + 124 * MB);   // 16MB
  unsigned short* VT    = (unsigned short*)(ws + 140 * MB);   // 16MB, live thru PV
  unsigned short* WvT   = (unsigned short*)(ws + 156 * MB);   // 2MB, dead after Vproj
  float*          MTpart= (float*)(ws + 158 * MB);            // 16MB f32, dead after reduce
  float*          Sc    = (float*)(ws + 0);                   // 64MB alias over dead region

  // --- precision prep ---
  split_w_kernel<<<dim3(512, 1, 2), 256, 0, stream>>>(Wk, Wq, Wkh, Wkl, Wqh, Wql);
  convert_wv_kernel<<<dim3(16, 16), 256, 0, stream>>>(Wv, WvT);
  convert_x_kernel<<<dim3(4096, 1, 3), 256, 0, stream>>>(Xk, Xq, Xv, Xkh, Xkl,
                                                         Xqh, Xql, Xvh);

  // --- M^T = Wk . Wq^T, split-K over 4 256-wide K-slices, f32 partials ---
  gemm_db_kernel<3, 0, false, false><<<dim3(8, 8, 4), 256, 0, stream>>>(
      Wkh, Wkl, Wqh, Wql, 1024, 1024, 256, MTpart, nullptr, nullptr, 1024,
      256, 256, (size_t)1024 * 1024);
  reduce_mt_kernel<<<dim3(1024), 256, 0, stream>>>(MTpart, MThi, MTlo);

  // --- T = Xq . MT^T (3-term, hi+lo out) ---
  gemm_db_kernel<3, 1, false, false><<<dim3(8, 64, 1), 256, 0, stream>>>(
      Xqh, Xql, MThi, MTlo, 1024, 1024, 1024, nullptr, Thi, Tlo, 1024, 0, 0, 0);

  // --- V = Xv . Wv (plain bf16 1-term; hi out) ---
  gemm_db_kernel<1, 2, false, false><<<dim3(8, 64, 1), 256, 0, stream>>>(
      Xvh, nullptr, WvT, nullptr, 1024, 1024, 1024, nullptr, Vhi, nullptr,
      1024, 0, 0, 0);

  transpose_v_kernel<<<dim3(16, 32, 4), 256, 0, stream>>>(Vhi, VT);

  // --- scores = T . Xk^T (raw), packed lower-triangle tiles, f32 out ---
  gemm_db_kernel<3, 0, true, false><<<dim3(136, 1, 4), 256, 0, stream>>>(
      Thi, Tlo, Xkh, Xkl, 1024, 1024, 1024, Sc, nullptr, nullptr, 2048,
      (size_t)2048 * 1024, (size_t)2048 * 1024, (size_t)2048 * 2048);

  softmax_kernel<<<dim3(8192), 256, 0, stream>>>(Sc);

  // --- out = P . V (P bf16 pitch 4096, VT K-major), K stops at diagonal ---
  gemm_db_kernel<1, 0, false, true><<<dim3(8, 16, 4), 256, 0, stream>>>(
      (const unsigned short*)Sc, nullptr, VT, nullptr, 4096, 2048, 2048,
      out, nullptr, nullptr, 1024, (size_t)2048 * 4096, (size_t)1024 * 2048,
      (size_t)2048 * 1024);
}

// Round 7
// 256.764 us; speedup vs baseline: 1.3587x; 1.0123x over previous
//
#include <hip/hip_runtime.h>
#include <math.h>

using f32x4  = __attribute__((ext_vector_type(4))) float;
using bf16x8 = __attribute__((ext_vector_type(8))) short;
using u16x8  = __attribute__((ext_vector_type(8))) unsigned short;
using u16x4  = __attribute__((ext_vector_type(4))) unsigned short;

static __device__ __forceinline__ unsigned short f2bf(float f) {
  unsigned int u = __builtin_bit_cast(unsigned int, f);
  u += 0x7FFFu + ((u >> 16) & 1u);
  return (unsigned short)(u >> 16);
}
static __device__ __forceinline__ float bf2f(unsigned short h) {
  unsigned int u = ((unsigned int)h) << 16;
  return __builtin_bit_cast(float, u);
}

// async global->LDS, 16B per lane. LDS dest is wave-uniform base; HW appends
// lane*16.
static __device__ __forceinline__ void gll16(const void* g, void* l) {
  using GPtr = const unsigned int __attribute__((address_space(1)))*;
  using LPtr = unsigned int __attribute__((address_space(3)))*;
  __builtin_amdgcn_global_load_lds((GPtr)(unsigned long long)g,
                                   (LPtr)(unsigned)(unsigned long long)l,
                                   16, 0, 0);
}

// Stage one [128][BK] bf16 tile (rule #21: linear LDS dest, pre-swizzled
// global source). Wave w stages rows [32w, 32w+32).
// BK=64: rows are 128B lines; slot (16B) XOR row&7.        [proven 0-conflict]
// BK=32: PAIRED-ROW layout — 64 lines x 128B, line holds logical rows
//        {2L, 2L+1}; logical q = (row&1)<<2 | kblock; physical slot
//        p = q ^ (line&7). Bank-equivalent to the BK=64 layout.
template <int BK>
static __device__ __forceinline__ void stageT(unsigned short* sdst,
                                              const unsigned short* g,
                                              size_t ld, int k0, int wave,
                                              int lane) {
  if constexpr (BK == 64) {
    const int r = lane >> 3, c8 = lane & 7;
    const int scol = (c8 ^ r) << 3;
#pragma unroll
    for (int i = 0; i < 4; ++i)
      gll16(g + (size_t)(wave * 32 + i * 8 + r) * ld + (k0 + scol),
            sdst + wave * 2048 + i * 512);
  } else {
    const int p = lane & 7;    // physical 16B slot in line
    const int ll = lane >> 3;  // local line 0..7
#pragma unroll
    for (int i = 0; i < 2; ++i) {
      const int line = wave * 16 + i * 8 + ll;  // global line 0..63
      const int q = p ^ (line & 7);
      const int srow = 2 * line + (q >> 2);
      const int scol = (q & 3) << 3;
      gll16(g + (size_t)srow * ld + (k0 + scol), sdst + wave * 1024 + i * 512);
    }
  }
}

// Swizzled fragment read matching stageT's layout.
template <int BK>
static __device__ __forceinline__ bf16x8 fragT(const unsigned short* s,
                                               int row, int kko) {
  if constexpr (BK == 64) {
    return *(const bf16x8*)&s[row * 64 + (kko ^ ((row & 7) << 3))];
  } else {
    const int line = row >> 1;
    const int q = ((row & 1) << 2) | (kko >> 3);
    const int p = q ^ (line & 7);
    return *(const bf16x8*)&s[line * 64 + p * 8];
  }
}

// ---------------------------------------------------------------------------
// Elementwise split: W [1024x1024] f32 -> Wh/Wl bf16 (ORIGINAL layout).
// z: 0 = Wk, 1 = Wq.
// ---------------------------------------------------------------------------
__global__ __launch_bounds__(256) void split_w_kernel(
    const float* __restrict__ Wk, const float* __restrict__ Wq,
    unsigned short* __restrict__ Wkh, unsigned short* __restrict__ Wkl,
    unsigned short* __restrict__ Wqh, unsigned short* __restrict__ Wql) {
  const int z = blockIdx.z;
  const float* W = (z == 0) ? Wk : Wq;
  unsigned short* H = (z == 0) ? Wkh : Wqh;
  unsigned short* L = (z == 0) ? Wkl : Wql;
  const size_t base = ((size_t)blockIdx.x * 256 + threadIdx.x) * 8;
  float av[8];
  *(f32x4*)&av[0] = *(const f32x4*)&W[base];
  *(f32x4*)&av[4] = *(const f32x4*)&W[base + 4];
  u16x8 h, l;
#pragma unroll
  for (int e = 0; e < 8; ++e) {
    unsigned short hh = f2bf(av[e]);
    h[e] = hh;
    l[e] = f2bf(av[e] - bf2f(hh));
  }
  *(u16x8*)&H[base] = h;
  *(u16x8*)&L[base] = l;
}

// ---------------------------------------------------------------------------
// Wv [1024 i][1024 o] f32 -> WvT [1024 o][1024 i] bf16 hi (transposed)
// ---------------------------------------------------------------------------
__global__ __launch_bounds__(256) void convert_wv_kernel(
    const float* __restrict__ Wv, unsigned short* __restrict__ WvT) {
  __shared__ float sW[64][65];
  const int ti = blockIdx.x * 64;
  const int tj = blockIdx.y * 64;
  const int tid = threadIdx.x;
#pragma unroll
  for (int it = 0; it < 4; ++it) {
    int idx = tid + it * 256;
    int r = idx >> 4, c = (idx & 15) << 2;
    f32x4 v = *(const f32x4*)&Wv[(size_t)(ti + r) * 1024 + tj + c];
    sW[r][c] = v[0]; sW[r][c + 1] = v[1]; sW[r][c + 2] = v[2]; sW[r][c + 3] = v[3];
  }
  __syncthreads();
#pragma unroll
  for (int it = 0; it < 4; ++it) {
    int idx = tid + it * 256;
    int ro = idx >> 4, ci = (idx & 15) << 2;
    u16x4 h;
#pragma unroll
    for (int e = 0; e < 4; ++e) h[e] = f2bf(sW[ci + e][ro]);
    *(u16x4*)&WvT[(size_t)(tj + ro) * 1024 + ti + ci] = h;
  }
}

// ---------------------------------------------------------------------------
// X [8192 x 1024] f32 -> Xh (+Xl for z<2) bf16, same layout.
// z: 0 = keys, 1 = queries, 2 = values.
// ---------------------------------------------------------------------------
__global__ __launch_bounds__(256) void convert_x_kernel(
    const float* __restrict__ Xk, const float* __restrict__ Xq,
    const float* __restrict__ Xv, unsigned short* __restrict__ Xkh,
    unsigned short* __restrict__ Xkl, unsigned short* __restrict__ Xqh,
    unsigned short* __restrict__ Xql, unsigned short* __restrict__ Xvh) {
  const int z = blockIdx.z;
  const float* X = (z == 0) ? Xk : (z == 1) ? Xq : Xv;
  unsigned short* H = (z == 0) ? Xkh : (z == 1) ? Xqh : Xvh;
  unsigned short* L = (z == 0) ? Xkl : Xql;
  const size_t base = ((size_t)blockIdx.x * 256 + threadIdx.x) * 8;
  float av[8];
  *(f32x4*)&av[0] = *(const f32x4*)&X[base];
  *(f32x4*)&av[4] = *(const f32x4*)&X[base + 4];
  u16x8 h, l;
#pragma unroll
  for (int e = 0; e < 8; ++e) {
    unsigned short hh = f2bf(av[e]);
    h[e] = hh;
    l[e] = f2bf(av[e] - bf2f(hh));
  }
  *(u16x8*)&H[base] = h;
  if (z < 2) *(u16x8*)&L[base] = l;
}

// ---------------------------------------------------------------------------
// Unified split-bf16 GEMM with 2-phase double-buffered global_load_lds
// staging (T3-minimum) + bijective XCD block swizzle (T1).
// 128x128 tile, 4 waves. NTERMS==3: BK=32 paired-row tiles, 4 tiles/buf;
// NTERMS==1: BK=64, 2 tiles/buf. LDS = 64KB either way (2 blocks/CU).
// Per step: issue next-tile stages -> compute current -> __syncthreads()
// (implicit vmcnt(0) drain lands AFTER compute, hiding stage latency).
// C = A * B^T, A rows = out rows, B rows = out cols, K-major.
// EPI: 0 = f32 C ; 1 = bf16 hi+lo ; 2 = bf16 hi.
// PACKED: lid%gx is a packed lower-triangle tile index.
// PVK: K-loop ends at (bm+1)*128.
// ---------------------------------------------------------------------------
template <int NTERMS, int EPI, bool PACKED, bool PVK>
__global__ __launch_bounds__(256, 2) void gemm_db_kernel(
    const unsigned short* __restrict__ Ah, const unsigned short* __restrict__ Al,
    const unsigned short* __restrict__ Bh, const unsigned short* __restrict__ Bl,
    size_t lda, size_t ldb, int K,
    float* __restrict__ Cf, unsigned short* __restrict__ Ch,
    unsigned short* __restrict__ Cl, size_t ldc,
    size_t abatch, size_t bbatch, size_t cbatch) {
  constexpr int BK = (NTERMS == 3) ? 32 : 64;
  constexpr int NTILES = (NTERMS == 3) ? 4 : 2;
  constexpr int TILE = 128 * BK;  // shorts per tile
  __shared__ unsigned short smem[2][NTILES * TILE];

  // Bijective XCD-chunked swizzle over the full linearized grid (m204).
  int lid = blockIdx.x + gridDim.x * (blockIdx.y + gridDim.y * blockIdx.z);
  {
    const int n = gridDim.x * gridDim.y * gridDim.z;
    const int q = n >> 3, r = n & 7, x = lid & 7, k = lid >> 3;
    lid = (x < r ? x * (q + 1) : r * (q + 1) + (x - r) * q) + k;
  }
  int bm, bn, b;
  if constexpr (PACKED) {
    const int t = lid % gridDim.x;
    b = lid / gridDim.x;
    bm = (int)((sqrtf(8.f * (float)t + 1.f) - 1.f) * 0.5f);
    while ((bm + 1) * (bm + 2) / 2 <= t) ++bm;
    while (bm * (bm + 1) / 2 > t) --bm;
    bn = t - bm * (bm + 1) / 2;
  } else {
    bn = lid % gridDim.x;
    const int tmp = lid / gridDim.x;
    bm = tmp % gridDim.y;
    b = tmp / gridDim.y;
  }
  const int tid = threadIdx.x, lane = tid & 63, wave = tid >> 6;
  const unsigned short* gA = Ah + abatch * b + (size_t)(bm * 128) * lda;
  const unsigned short* gB = Bh + bbatch * b + (size_t)(bn * 128) * ldb;
  const unsigned short* gAl2 =
      (NTERMS == 3) ? Al + abatch * b + (size_t)(bm * 128) * lda : nullptr;
  const unsigned short* gBl2 =
      (NTERMS == 3) ? Bl + bbatch * b + (size_t)(bn * 128) * ldb : nullptr;
  const int kend = PVK ? (bm + 1) * 128 : K;
  const int nsteps = kend / BK;
  f32x4 acc[4][4] = {};
  const int wr = (wave >> 1) << 6, wc = (wave & 1) << 6;
  const int frow = lane & 15, koff = (lane >> 4) << 3;

  auto stage_all = [&](unsigned short* buf, int k0) {
    stageT<BK>(buf, gA, lda, k0, wave, lane);
    stageT<BK>(buf + TILE, gB, ldb, k0, wave, lane);
    if constexpr (NTERMS == 3) {
      stageT<BK>(buf + 2 * TILE, gBl2, ldb, k0, wave, lane);
      stageT<BK>(buf + 3 * TILE, gAl2, lda, k0, wave, lane);
    }
  };

  stage_all(smem[0], 0);
  __syncthreads();  // implicit vmcnt(0): buf0 ready
  int cur = 0;
  for (int st = 0; st < nsteps; ++st) {
    if (st + 1 < nsteps) stage_all(smem[cur ^ 1], (st + 1) * BK);  // async
    const unsigned short* sA = smem[cur];
    const unsigned short* sB = smem[cur] + TILE;
    if constexpr (NTERMS == 3) {
      const unsigned short* sBl = smem[cur] + 2 * TILE;
      const unsigned short* sAl = smem[cur] + 3 * TILE;
      bf16x8 fBh[4], fBl[4];
#pragma unroll
      for (int j = 0; j < 4; ++j) {
        fBh[j] = fragT<BK>(sB, wc + j * 16 + frow, koff);
        fBl[j] = fragT<BK>(sBl, wc + j * 16 + frow, koff);
      }
#pragma unroll
      for (int i = 0; i < 4; ++i) {
        const bf16x8 ah = fragT<BK>(sA, wr + i * 16 + frow, koff);
        const bf16x8 al = fragT<BK>(sAl, wr + i * 16 + frow, koff);
#pragma unroll
        for (int j = 0; j < 4; ++j) {
          acc[i][j] = __builtin_amdgcn_mfma_f32_16x16x32_bf16(ah, fBh[j], acc[i][j], 0, 0, 0);
          acc[i][j] = __builtin_amdgcn_mfma_f32_16x16x32_bf16(ah, fBl[j], acc[i][j], 0, 0, 0);
          acc[i][j] = __builtin_amdgcn_mfma_f32_16x16x32_bf16(al, fBh[j], acc[i][j], 0, 0, 0);
        }
      }
    } else {
#pragma unroll
      for (int kk = 0; kk < 64; kk += 32) {
        const int kko = kk + koff;
        bf16x8 fBh[4];
#pragma unroll
        for (int j = 0; j < 4; ++j) fBh[j] = fragT<BK>(sB, wc + j * 16 + frow, kko);
#pragma unroll
        for (int i = 0; i < 4; ++i) {
          const bf16x8 ah = fragT<BK>(sA, wr + i * 16 + frow, kko);
#pragma unroll
          for (int j = 0; j < 4; ++j)
            acc[i][j] = __builtin_amdgcn_mfma_f32_16x16x32_bf16(ah, fBh[j], acc[i][j], 0, 0, 0);
        }
      }
    }
    __syncthreads();  // implicit vmcnt(0): next buffer staged, reads done
    cur ^= 1;
  }

  const int erow = bm * 128 + wr + ((lane >> 4) << 2);
  const int ecol = bn * 128 + wc + frow;
  if constexpr (EPI == 0) {
    float* C = Cf + cbatch * b;
#pragma unroll
    for (int i = 0; i < 4; ++i)
#pragma unroll
      for (int j = 0; j < 4; ++j)
#pragma unroll
        for (int e = 0; e < 4; ++e)
          C[(size_t)(erow + i * 16 + e) * ldc + (ecol + j * 16)] = acc[i][j][e];
  } else {
    unsigned short* Cho = Ch + cbatch * b;
    unsigned short* Clo = (EPI == 1) ? Cl + cbatch * b : nullptr;
#pragma unroll
    for (int i = 0; i < 4; ++i)
#pragma unroll
      for (int j = 0; j < 4; ++j)
#pragma unroll
        for (int e = 0; e < 4; ++e) {
          size_t off = (size_t)(erow + i * 16 + e) * ldc + (ecol + j * 16);
          float v = acc[i][j][e];
          unsigned short hh = f2bf(v);
          Cho[off] = hh;
          if constexpr (EPI == 1) Clo[off] = f2bf(v - bf2f(hh));
        }
  }
}

// ---------------------------------------------------------------------------
// Sum 4 split-K partials of MT (f32) -> MThi/MTlo bf16 split. [1024x1024]
// ---------------------------------------------------------------------------
__global__ __launch_bounds__(256) void reduce_mt_kernel(
    const float* __restrict__ P, unsigned short* __restrict__ H,
    unsigned short* __restrict__ L) {
  const size_t base = ((size_t)blockIdx.x * 256 + threadIdx.x) * 4;
  f32x4 s = *(const f32x4*)&P[base];
#pragma unroll
  for (int z = 1; z < 4; ++z) {
    f32x4 v = *(const f32x4*)&P[(size_t)z * 1048576 + base];
    s[0] += v[0]; s[1] += v[1]; s[2] += v[2]; s[3] += v[3];
  }
  u16x4 h, l;
#pragma unroll
  for (int e = 0; e < 4; ++e) {
    unsigned short hh = f2bf(s[e]);
    h[e] = hh;
    l[e] = f2bf(s[e] - bf2f(hh));
  }
  *(u16x4*)&H[base] = h;
  *(u16x4*)&L[base] = l;
}

// ---------------------------------------------------------------------------
// V [b][2048 s][1024 o] bf16 -> VT [b][1024 o][2048 s] bf16
// ---------------------------------------------------------------------------
__global__ __launch_bounds__(256) void transpose_v_kernel(
    const unsigned short* __restrict__ V, unsigned short* __restrict__ VT) {
  __shared__ unsigned short sV[64][72];
  const int ox = blockIdx.x, sy = blockIdx.y, b = blockIdx.z;
  const int tid = threadIdx.x;
#pragma unroll
  for (int it = 0; it < 2; ++it) {
    int idx = tid + it * 256;
    int r = idx >> 3, c8 = (idx & 7) << 3;
    u16x8 v = *(const u16x8*)&V[((size_t)b * 2048 + sy * 64 + r) * 1024 + ox * 64 + c8];
#pragma unroll
    for (int e = 0; e < 8; ++e) sV[r][c8 + e] = v[e];
  }
  __syncthreads();
#pragma unroll
  for (int it = 0; it < 2; ++it) {
    int idx = tid + it * 256;
    int ro = idx >> 3, cs = (idx & 7) << 3;
    u16x8 w;
#pragma unroll
    for (int e = 0; e < 8; ++e) w[e] = sV[cs + e][ro];
    *(u16x8*)&VT[((size_t)b * 1024 + ox * 64 + ro) * 2048 + sy * 64 + cs] = w;
  }
}

// ---------------------------------------------------------------------------
// Row softmax with causal mask + 1/sqrt(d) scale. Writes bf16 P in-place over
// the f32 scores buffer. Safe: reads complete before first barrier.
// ---------------------------------------------------------------------------
__global__ __launch_bounds__(256) void softmax_kernel(float* __restrict__ Sc) {
  const int row = blockIdx.x;  // b*2048 + q
  const int q = row & 2047;
  const int tid = threadIdx.x, lane = tid & 63, wave = tid >> 6;
  float* srow = Sc + (size_t)row * 2048;
  unsigned short* prow = (unsigned short*)srow;
  const int k0 = tid * 4, k1 = 1024 + tid * 4;
  f32x4 v0 = {}, v1 = {};
  if (k0 <= q) v0 = *(const f32x4*)(srow + k0);
  if (k1 <= q) v1 = *(const f32x4*)(srow + k1);
  float m = -3.0e38f;
#pragma unroll
  for (int e = 0; e < 4; ++e) {
    if (k0 + e <= q) m = fmaxf(m, v0[e]);
    if (k1 + e <= q) m = fmaxf(m, v1[e]);
  }
#pragma unroll
  for (int o = 32; o; o >>= 1) m = fmaxf(m, __shfl_xor(m, o));
  __shared__ float redm[4], reds[4];
  if (lane == 0) redm[wave] = m;
  __syncthreads();
  m = fmaxf(fmaxf(redm[0], redm[1]), fmaxf(redm[2], redm[3]));
  const float scale = 0.03125f;  // 1/sqrt(1024)
  float p[8];
  float s = 0.f;
#pragma unroll
  for (int e = 0; e < 4; ++e) {
    p[e] = (k0 + e <= q) ? __expf((v0[e] - m) * scale) : 0.f;
    p[4 + e] = (k1 + e <= q) ? __expf((v1[e] - m) * scale) : 0.f;
    s += p[e] + p[4 + e];
  }
#pragma unroll
  for (int o = 32; o; o >>= 1) s += __shfl_xor(s, o);
  if (lane == 0) reds[wave] = s;
  __syncthreads();
  s = reds[0] + reds[1] + reds[2] + reds[3];
  const float inv = 1.0f / s;
  u16x4 o0, o1;
#pragma unroll
  for (int e = 0; e < 4; ++e) {
    o0[e] = f2bf(p[e] * inv);
    o1[e] = f2bf(p[4 + e] * inv);
  }
  *(u16x4*)&prow[k0] = o0;
  *(u16x4*)&prow[k1] = o1;
}

// ---------------------------------------------------------------------------
extern "C" void kernel_launch(void* const* d_in, const int* in_sizes, int n_in,
                              void* d_out, int out_size, void* d_ws, size_t ws_size,
                              hipStream_t stream) {
  const float* Xk = (const float*)d_in[0];
  const float* Xv = (const float*)d_in[1];
  const float* Xq = (const float*)d_in[2];
  const float* Wk = (const float*)d_in[3];
  const float* Wv = (const float*)d_in[4];
  const float* Wq = (const float*)d_in[5];
  float* out = (float*)d_out;

  char* ws = (char*)d_ws;
  const size_t MB = 1024ull * 1024;
  // Liveness-planned layout (174 MB total). [0,64MB) is dead by scores time
  // and is reused for Sc.
  unsigned short* Xqh   = (unsigned short*)(ws + 0);          // 16MB, dead after T
  unsigned short* Xvh   = (unsigned short*)(ws + 16 * MB);    // 16MB, dead after Vproj
  unsigned short* Xql   = (unsigned short*)(ws + 32 * MB);    // 16MB, dead after T
  unsigned short* Wkh   = (unsigned short*)(ws + 48 * MB);    // 2MB, dead after M
  unsigned short* Wkl   = (unsigned short*)(ws + 50 * MB);
  unsigned short* Wqh   = (unsigned short*)(ws + 52 * MB);
  unsigned short* Wql   = (unsigned short*)(ws + 54 * MB);
  unsigned short* MThi  = (unsigned short*)(ws + 56 * MB);    // 2MB, dead after T
  unsigned short* MTlo  = (unsigned short*)(ws + 58 * MB);
  unsigned short* Vhi   = (unsigned short*)(ws + 60 * MB);    // 16MB, dead after transpose
  unsigned short* Xkh   = (unsigned short*)(ws + 76 * MB);    // 16MB, live thru scores
  unsigned short* Xkl   = (unsigned short*)(ws + 92 * MB);    // 16MB
  unsigned short* Thi   = (unsigned short*)(ws + 108 * MB);   // 16MB, live thru scores
  unsigned short* Tlo   = (unsigned short*)(ws + 124 * MB);   // 16MB
  unsigned short* VT    = (unsigned short*)(ws + 140 * MB);   // 16MB, live thru PV
  unsigned short* WvT   = (unsigned short*)(ws + 156 * MB);   // 2MB, dead after Vproj
  float*          MTpart= (float*)(ws + 158 * MB);            // 16MB f32, dead after reduce
  float*          Sc    = (float*)(ws + 0);                   // 64MB alias over dead region

  // --- precision prep ---
  split_w_kernel<<<dim3(512, 1, 2), 256, 0, stream>>>(Wk, Wq, Wkh, Wkl, Wqh, Wql);
  convert_wv_kernel<<<dim3(16, 16), 256, 0, stream>>>(Wv, WvT);
  convert_x_kernel<<<dim3(4096, 1, 3), 256, 0, stream>>>(Xk, Xq, Xv, Xkh, Xkl,
                                                         Xqh, Xql, Xvh);

  // --- M^T = Wk . Wq^T, split-K over 4 256-wide K-slices, f32 partials ---
  gemm_db_kernel<3, 0, false, false><<<dim3(8, 8, 4), 256, 0, stream>>>(
      Wkh, Wkl, Wqh, Wql, 1024, 1024, 256, MTpart, nullptr, nullptr, 1024,
      256, 256, (size_t)1024 * 1024);
  reduce_mt_kernel<<<dim3(1024), 256, 0, stream>>>(MTpart, MThi, MTlo);

  // --- T = Xq . MT^T (3-term, hi+lo out) ---
  gemm_db_kernel<3, 1, false, false><<<dim3(8, 64, 1), 256, 0, stream>>>(
      Xqh, Xql, MThi, MTlo, 1024, 1024, 1024, nullptr, Thi, Tlo, 1024, 0, 0, 0);

  // --- V = Xv . Wv (plain bf16 1-term; hi out) ---
  gemm_db_kernel<1, 2, false, false><<<dim3(8, 64, 1), 256, 0, stream>>>(
      Xvh, nullptr, WvT, nullptr, 1024, 1024, 1024, nullptr, Vhi, nullptr,
      1024, 0, 0, 0);

  transpose_v_kernel<<<dim3(16, 32, 4), 256, 0, stream>>>(Vhi, VT);

  // --- scores = T . Xk^T (raw), packed lower-triangle tiles, f32 out ---
  gemm_db_kernel<3, 0, true, false><<<dim3(136, 1, 4), 256, 0, stream>>>(
      Thi, Tlo, Xkh, Xkl, 1024, 1024, 1024, Sc, nullptr, nullptr, 2048,
      (size_t)2048 * 1024, (size_t)2048 * 1024, (size_t)2048 * 2048);

  softmax_kernel<<<dim3(8192), 256, 0, stream>>>(Sc);

  // --- out = P . V (P bf16 pitch 4096, VT K-major), K stops at diagonal ---
  gemm_db_kernel<1, 0, false, true><<<dim3(8, 16, 4), 256, 0, stream>>>(
      (const unsigned short*)Sc, nullptr, VT, nullptr, 4096, 2048, 2048,
      out, nullptr, nullptr, 1024, (size_t)2048 * 4096, (size_t)1024 * 2048,
      (size_t)2048 * 1024);
}

// Round 8
// 246.257 us; speedup vs baseline: 1.4166x; 1.0427x over previous
//
#include <hip/hip_runtime.h>
#include <math.h>

using f32x4  = __attribute__((ext_vector_type(4))) float;
using bf16x8 = __attribute__((ext_vector_type(8))) short;
using u16x8  = __attribute__((ext_vector_type(8))) unsigned short;
using u16x4  = __attribute__((ext_vector_type(4))) unsigned short;

static __device__ __forceinline__ unsigned short f2bf(float f) {
  unsigned int u = __builtin_bit_cast(unsigned int, f);
  u += 0x7FFFu + ((u >> 16) & 1u);
  return (unsigned short)(u >> 16);
}
static __device__ __forceinline__ float bf2f(unsigned short h) {
  unsigned int u = ((unsigned int)h) << 16;
  return __builtin_bit_cast(float, u);
}

// async global->LDS, 16B per lane. LDS dest is wave-uniform base; HW appends
// lane*16.
static __device__ __forceinline__ void gll16(const void* g, void* l) {
  using GPtr = const unsigned int __attribute__((address_space(1)))*;
  using LPtr = unsigned int __attribute__((address_space(3)))*;
  __builtin_amdgcn_global_load_lds((GPtr)(unsigned long long)g,
                                   (LPtr)(unsigned)(unsigned long long)l,
                                   16, 0, 0);
}

// Stage one [128][BK] bf16 tile (rule #21: linear LDS dest, pre-swizzled
// global source). Wave w stages rows [32w, 32w+32).
// BK=64: rows are 128B lines; slot (16B) XOR row&7.        [proven 0-conflict]
// BK=32: PAIRED-ROW layout — 64 lines x 128B, line holds logical rows
//        {2L, 2L+1}; logical q = (row&1)<<2 | kblock; physical slot
//        p = q ^ (line&7). Bank-equivalent to the BK=64 layout. [r7: 0-conflict]
// Loads issued per wave per tile: BK=64 -> 4, BK=32 -> 2.
template <int BK>
static __device__ __forceinline__ void stageT(unsigned short* sdst,
                                              const unsigned short* g,
                                              size_t ld, int k0, int wave,
                                              int lane) {
  if constexpr (BK == 64) {
    const int r = lane >> 3, c8 = lane & 7;
    const int scol = (c8 ^ r) << 3;
#pragma unroll
    for (int i = 0; i < 4; ++i)
      gll16(g + (size_t)(wave * 32 + i * 8 + r) * ld + (k0 + scol),
            sdst + wave * 2048 + i * 512);
  } else {
    const int p = lane & 7;    // physical 16B slot in line
    const int ll = lane >> 3;  // local line 0..7
#pragma unroll
    for (int i = 0; i < 2; ++i) {
      const int line = wave * 16 + i * 8 + ll;  // global line 0..63
      const int q = p ^ (line & 7);
      const int srow = 2 * line + (q >> 2);
      const int scol = (q & 3) << 3;
      gll16(g + (size_t)srow * ld + (k0 + scol), sdst + wave * 1024 + i * 512);
    }
  }
}

// Swizzled fragment read matching stageT's layout.
template <int BK>
static __device__ __forceinline__ bf16x8 fragT(const unsigned short* s,
                                               int row, int kko) {
  if constexpr (BK == 64) {
    return *(const bf16x8*)&s[row * 64 + (kko ^ ((row & 7) << 3))];
  } else {
    const int line = row >> 1;
    const int q = ((row & 1) << 2) | (kko >> 3);
    const int p = q ^ (line & 7);
    return *(const bf16x8*)&s[line * 64 + p * 8];
  }
}

// ---------------------------------------------------------------------------
// Elementwise split: W [1024x1024] f32 -> Wh/Wl bf16 (ORIGINAL layout).
// z: 0 = Wk, 1 = Wq.
// ---------------------------------------------------------------------------
__global__ __launch_bounds__(256) void split_w_kernel(
    const float* __restrict__ Wk, const float* __restrict__ Wq,
    unsigned short* __restrict__ Wkh, unsigned short* __restrict__ Wkl,
    unsigned short* __restrict__ Wqh, unsigned short* __restrict__ Wql) {
  const int z = blockIdx.z;
  const float* W = (z == 0) ? Wk : Wq;
  unsigned short* H = (z == 0) ? Wkh : Wqh;
  unsigned short* L = (z == 0) ? Wkl : Wql;
  const size_t base = ((size_t)blockIdx.x * 256 + threadIdx.x) * 8;
  float av[8];
  *(f32x4*)&av[0] = *(const f32x4*)&W[base];
  *(f32x4*)&av[4] = *(const f32x4*)&W[base + 4];
  u16x8 h, l;
#pragma unroll
  for (int e = 0; e < 8; ++e) {
    unsigned short hh = f2bf(av[e]);
    h[e] = hh;
    l[e] = f2bf(av[e] - bf2f(hh));
  }
  *(u16x8*)&H[base] = h;
  *(u16x8*)&L[base] = l;
}

// ---------------------------------------------------------------------------
// Wv [1024 i][1024 o] f32 -> WvT [1024 o][1024 i] bf16 hi (transposed)
// ---------------------------------------------------------------------------
__global__ __launch_bounds__(256) void convert_wv_kernel(
    const float* __restrict__ Wv, unsigned short* __restrict__ WvT) {
  __shared__ float sW[64][65];
  const int ti = blockIdx.x * 64;
  const int tj = blockIdx.y * 64;
  const int tid = threadIdx.x;
#pragma unroll
  for (int it = 0; it < 4; ++it) {
    int idx = tid + it * 256;
    int r = idx >> 4, c = (idx & 15) << 2;
    f32x4 v = *(const f32x4*)&Wv[(size_t)(ti + r) * 1024 + tj + c];
    sW[r][c] = v[0]; sW[r][c + 1] = v[1]; sW[r][c + 2] = v[2]; sW[r][c + 3] = v[3];
  }
  __syncthreads();
#pragma unroll
  for (int it = 0; it < 4; ++it) {
    int idx = tid + it * 256;
    int ro = idx >> 4, ci = (idx & 15) << 2;
    u16x4 h;
#pragma unroll
    for (int e = 0; e < 4; ++e) h[e] = f2bf(sW[ci + e][ro]);
    *(u16x4*)&WvT[(size_t)(tj + ro) * 1024 + ti + ci] = h;
  }
}

// ---------------------------------------------------------------------------
// X [8192 x 1024] f32 -> Xh (+Xl for z<2) bf16, same layout.
// z: 0 = keys, 1 = queries, 2 = values.
// ---------------------------------------------------------------------------
__global__ __launch_bounds__(256) void convert_x_kernel(
    const float* __restrict__ Xk, const float* __restrict__ Xq,
    const float* __restrict__ Xv, unsigned short* __restrict__ Xkh,
    unsigned short* __restrict__ Xkl, unsigned short* __restrict__ Xqh,
    unsigned short* __restrict__ Xql, unsigned short* __restrict__ Xvh) {
  const int z = blockIdx.z;
  const float* X = (z == 0) ? Xk : (z == 1) ? Xq : Xv;
  unsigned short* H = (z == 0) ? Xkh : (z == 1) ? Xqh : Xvh;
  unsigned short* L = (z == 0) ? Xkl : Xql;
  const size_t base = ((size_t)blockIdx.x * 256 + threadIdx.x) * 8;
  float av[8];
  *(f32x4*)&av[0] = *(const f32x4*)&X[base];
  *(f32x4*)&av[4] = *(const f32x4*)&X[base + 4];
  u16x8 h, l;
#pragma unroll
  for (int e = 0; e < 8; ++e) {
    unsigned short hh = f2bf(av[e]);
    h[e] = hh;
    l[e] = f2bf(av[e] - bf2f(hh));
  }
  *(u16x8*)&H[base] = h;
  if (z < 2) *(u16x8*)&L[base] = l;
}

// ---------------------------------------------------------------------------
// Unified split-bf16 GEMM, deep 2-buffer counted-vmcnt pipeline (T4):
// prologue stages BOTH buffers (16 loads in flight/wave); per step:
//   s_waitcnt vmcnt(8)   -- wait only the 8 loads issued 2 phases ago
//   s_barrier            -- all waves' portions of buf[cur] complete
//   ds_read + MFMA       -- compiler inserts lgkmcnt before MFMA use
//   lgkmcnt(0); s_barrier-- all waves done reading buf[cur]
//   restage buf[cur] for step st+2 (8 more loads; never drain to 0)
// Both configs issue exactly 8 global_load_lds/wave/step.
// 128x128 tile, 4 waves. NTERMS==3: BK=32 paired-row, 4 tiles/buf;
// NTERMS==1: BK=64, 2 tiles/buf. LDS 64KB, 2 blocks/CU. XCD swizzle (T1).
// EPI: 0 = f32 C ; 1 = bf16 hi+lo ; 2 = bf16 hi ; 3 = bf16 transposed into
// VT[4][1024][2048] (fused V-transpose).
// PACKED: lid%gx is a packed lower-triangle tile index.
// PVK: K-loop ends at (bm+1)*128.
// ---------------------------------------------------------------------------
template <int NTERMS, int EPI, bool PACKED, bool PVK>
__global__ __launch_bounds__(256, 2) void gemm_db_kernel(
    const unsigned short* __restrict__ Ah, const unsigned short* __restrict__ Al,
    const unsigned short* __restrict__ Bh, const unsigned short* __restrict__ Bl,
    size_t lda, size_t ldb, int K,
    float* __restrict__ Cf, unsigned short* __restrict__ Ch,
    unsigned short* __restrict__ Cl, size_t ldc,
    size_t abatch, size_t bbatch, size_t cbatch) {
  constexpr int BK = (NTERMS == 3) ? 32 : 64;
  constexpr int NTILES = (NTERMS == 3) ? 4 : 2;
  constexpr int TILE = 128 * BK;  // shorts per tile
  __shared__ unsigned short smem[2][NTILES * TILE];

  // Bijective XCD-chunked swizzle over the full linearized grid (m204).
  int lid = blockIdx.x + gridDim.x * (blockIdx.y + gridDim.y * blockIdx.z);
  {
    const int n = gridDim.x * gridDim.y * gridDim.z;
    const int q = n >> 3, r = n & 7, x = lid & 7, k = lid >> 3;
    lid = (x < r ? x * (q + 1) : r * (q + 1) + (x - r) * q) + k;
  }
  int bm, bn, b;
  if constexpr (PACKED) {
    const int t = lid % gridDim.x;
    b = lid / gridDim.x;
    bm = (int)((sqrtf(8.f * (float)t + 1.f) - 1.f) * 0.5f);
    while ((bm + 1) * (bm + 2) / 2 <= t) ++bm;
    while (bm * (bm + 1) / 2 > t) --bm;
    bn = t - bm * (bm + 1) / 2;
  } else {
    bn = lid % gridDim.x;
    const int tmp = lid / gridDim.x;
    bm = tmp % gridDim.y;
    b = tmp / gridDim.y;
  }
  const int tid = threadIdx.x, lane = tid & 63, wave = tid >> 6;
  const unsigned short* gA = Ah + abatch * b + (size_t)(bm * 128) * lda;
  const unsigned short* gB = Bh + bbatch * b + (size_t)(bn * 128) * ldb;
  const unsigned short* gAl2 =
      (NTERMS == 3) ? Al + abatch * b + (size_t)(bm * 128) * lda : nullptr;
  const unsigned short* gBl2 =
      (NTERMS == 3) ? Bl + bbatch * b + (size_t)(bn * 128) * ldb : nullptr;
  const int kend = PVK ? (bm + 1) * 128 : K;
  const int nsteps = kend / BK;
  f32x4 acc[4][4] = {};
  const int wr = (wave >> 1) << 6, wc = (wave & 1) << 6;
  const int frow = lane & 15, koff = (lane >> 4) << 3;

  auto stage_all = [&](unsigned short* buf, int k0) {
    stageT<BK>(buf, gA, lda, k0, wave, lane);
    stageT<BK>(buf + TILE, gB, ldb, k0, wave, lane);
    if constexpr (NTERMS == 3) {
      stageT<BK>(buf + 2 * TILE, gBl2, ldb, k0, wave, lane);
      stageT<BK>(buf + 3 * TILE, gAl2, lda, k0, wave, lane);
    }
  };

  stage_all(smem[0], 0);
  if (nsteps > 1) stage_all(smem[1], BK);
  int cur = 0;
  for (int st = 0; st < nsteps; ++st) {
    if (st + 1 < nsteps) {
      asm volatile("s_waitcnt vmcnt(8)" ::: "memory");
    } else {
      asm volatile("s_waitcnt vmcnt(0)" ::: "memory");
    }
    __builtin_amdgcn_sched_barrier(0);
    __builtin_amdgcn_s_barrier();  // buf[cur] fully in LDS (all waves)
    __builtin_amdgcn_sched_barrier(0);
    const unsigned short* sA = smem[cur];
    const unsigned short* sB = smem[cur] + TILE;
    if constexpr (NTERMS == 3) {
      const unsigned short* sBl = smem[cur] + 2 * TILE;
      const unsigned short* sAl = smem[cur] + 3 * TILE;
      bf16x8 fBh[4], fBl[4];
#pragma unroll
      for (int j = 0; j < 4; ++j) {
        fBh[j] = fragT<BK>(sB, wc + j * 16 + frow, koff);
        fBl[j] = fragT<BK>(sBl, wc + j * 16 + frow, koff);
      }
#pragma unroll
      for (int i = 0; i < 4; ++i) {
        const bf16x8 ah = fragT<BK>(sA, wr + i * 16 + frow, koff);
        const bf16x8 al = fragT<BK>(sAl, wr + i * 16 + frow, koff);
#pragma unroll
        for (int j = 0; j < 4; ++j) {
          acc[i][j] = __builtin_amdgcn_mfma_f32_16x16x32_bf16(ah, fBh[j], acc[i][j], 0, 0, 0);
          acc[i][j] = __builtin_amdgcn_mfma_f32_16x16x32_bf16(ah, fBl[j], acc[i][j], 0, 0, 0);
          acc[i][j] = __builtin_amdgcn_mfma_f32_16x16x32_bf16(al, fBh[j], acc[i][j], 0, 0, 0);
        }
      }
    } else {
#pragma unroll
      for (int kk = 0; kk < 64; kk += 32) {
        const int kko = kk + koff;
        bf16x8 fBh[4];
#pragma unroll
        for (int j = 0; j < 4; ++j) fBh[j] = fragT<BK>(sB, wc + j * 16 + frow, kko);
#pragma unroll
        for (int i = 0; i < 4; ++i) {
          const bf16x8 ah = fragT<BK>(sA, wr + i * 16 + frow, kko);
#pragma unroll
          for (int j = 0; j < 4; ++j)
            acc[i][j] = __builtin_amdgcn_mfma_f32_16x16x32_bf16(ah, fBh[j], acc[i][j], 0, 0, 0);
        }
      }
    }
    asm volatile("s_waitcnt lgkmcnt(0)" ::: "memory");
    __builtin_amdgcn_sched_barrier(0);
    __builtin_amdgcn_s_barrier();  // all waves done reading buf[cur]
    __builtin_amdgcn_sched_barrier(0);
    if (st + 2 < nsteps) stage_all(smem[cur], (st + 2) * BK);
    cur ^= 1;
  }

  const int erow = bm * 128 + wr + ((lane >> 4) << 2);
  const int ecol = bn * 128 + wc + frow;
  if constexpr (EPI == 0) {
    float* C = Cf + cbatch * b;
#pragma unroll
    for (int i = 0; i < 4; ++i)
#pragma unroll
      for (int j = 0; j < 4; ++j)
#pragma unroll
        for (int e = 0; e < 4; ++e)
          C[(size_t)(erow + i * 16 + e) * ldc + (ecol + j * 16)] = acc[i][j][e];
  } else if constexpr (EPI == 3) {
    // Fused V-transpose: Ch is VT[4][1024 o][2048 s]; rows s = erow+i*16+e,
    // cols o = ecol+j*16. Batch = s>>11 (tiles 128-aligned, batches
    // 2048-aligned, so the 4 consecutive s never cross a batch).
#pragma unroll
    for (int i = 0; i < 4; ++i)
#pragma unroll
      for (int j = 0; j < 4; ++j) {
        const int s = erow + i * 16;
        const int o = ecol + j * 16;
        u16x4 v;
#pragma unroll
        for (int e = 0; e < 4; ++e) v[e] = f2bf(acc[i][j][e]);
        *(u16x4*)&Ch[((size_t)(s >> 11) * 1024 + o) * 2048 + (s & 2047)] = v;
      }
  } else {
    unsigned short* Cho = Ch + cbatch * b;
    unsigned short* Clo = (EPI == 1) ? Cl + cbatch * b : nullptr;
#pragma unroll
    for (int i = 0; i < 4; ++i)
#pragma unroll
      for (int j = 0; j < 4; ++j)
#pragma unroll
        for (int e = 0; e < 4; ++e) {
          size_t off = (size_t)(erow + i * 16 + e) * ldc + (ecol + j * 16);
          float v = acc[i][j][e];
          unsigned short hh = f2bf(v);
          Cho[off] = hh;
          if constexpr (EPI == 1) Clo[off] = f2bf(v - bf2f(hh));
        }
  }
}

// ---------------------------------------------------------------------------
// Sum 4 split-K partials of MT (f32) -> MThi/MTlo bf16 split. [1024x1024]
// ---------------------------------------------------------------------------
__global__ __launch_bounds__(256) void reduce_mt_kernel(
    const float* __restrict__ P, unsigned short* __restrict__ H,
    unsigned short* __restrict__ L) {
  const size_t base = ((size_t)blockIdx.x * 256 + threadIdx.x) * 4;
  f32x4 s = *(const f32x4*)&P[base];
#pragma unroll
  for (int z = 1; z < 4; ++z) {
    f32x4 v = *(const f32x4*)&P[(size_t)z * 1048576 + base];
    s[0] += v[0]; s[1] += v[1]; s[2] += v[2]; s[3] += v[3];
  }
  u16x4 h, l;
#pragma unroll
  for (int e = 0; e < 4; ++e) {
    unsigned short hh = f2bf(s[e]);
    h[e] = hh;
    l[e] = f2bf(s[e] - bf2f(hh));
  }
  *(u16x4*)&H[base] = h;
  *(u16x4*)&L[base] = l;
}

// ---------------------------------------------------------------------------
// Row softmax with causal mask + 1/sqrt(d) scale. Writes bf16 P in-place over
// the f32 scores buffer. Safe: reads complete before first barrier.
// ---------------------------------------------------------------------------
__global__ __launch_bounds__(256) void softmax_kernel(float* __restrict__ Sc) {
  const int row = blockIdx.x;  // b*2048 + q
  const int q = row & 2047;
  const int tid = threadIdx.x, lane = tid & 63, wave = tid >> 6;
  float* srow = Sc + (size_t)row * 2048;
  unsigned short* prow = (unsigned short*)srow;
  const int k0 = tid * 4, k1 = 1024 + tid * 4;
  f32x4 v0 = {}, v1 = {};
  if (k0 <= q) v0 = *(const f32x4*)(srow + k0);
  if (k1 <= q) v1 = *(const f32x4*)(srow + k1);
  float m = -3.0e38f;
#pragma unroll
  for (int e = 0; e < 4; ++e) {
    if (k0 + e <= q) m = fmaxf(m, v0[e]);
    if (k1 + e <= q) m = fmaxf(m, v1[e]);
  }
#pragma unroll
  for (int o = 32; o; o >>= 1) m = fmaxf(m, __shfl_xor(m, o));
  __shared__ float redm[4], reds[4];
  if (lane == 0) redm[wave] = m;
  __syncthreads();
  m = fmaxf(fmaxf(redm[0], redm[1]), fmaxf(redm[2], redm[3]));
  const float scale = 0.03125f;  // 1/sqrt(1024)
  float p[8];
  float s = 0.f;
#pragma unroll
  for (int e = 0; e < 4; ++e) {
    p[e] = (k0 + e <= q) ? __expf((v0[e] - m) * scale) : 0.f;
    p[4 + e] = (k1 + e <= q) ? __expf((v1[e] - m) * scale) : 0.f;
    s += p[e] + p[4 + e];
  }
#pragma unroll
  for (int o = 32; o; o >>= 1) s += __shfl_xor(s, o);
  if (lane == 0) reds[wave] = s;
  __syncthreads();
  s = reds[0] + reds[1] + reds[2] + reds[3];
  const float inv = 1.0f / s;
  u16x4 o0, o1;
#pragma unroll
  for (int e = 0; e < 4; ++e) {
    o0[e] = f2bf(p[e] * inv);
    o1[e] = f2bf(p[4 + e] * inv);
  }
  *(u16x4*)&prow[k0] = o0;
  *(u16x4*)&prow[k1] = o1;
}

// ---------------------------------------------------------------------------
extern "C" void kernel_launch(void* const* d_in, const int* in_sizes, int n_in,
                              void* d_out, int out_size, void* d_ws, size_t ws_size,
                              hipStream_t stream) {
  const float* Xk = (const float*)d_in[0];
  const float* Xv = (const float*)d_in[1];
  const float* Xq = (const float*)d_in[2];
  const float* Wk = (const float*)d_in[3];
  const float* Wv = (const float*)d_in[4];
  const float* Wq = (const float*)d_in[5];
  float* out = (float*)d_out;

  char* ws = (char*)d_ws;
  const size_t MB = 1024ull * 1024;
  // Liveness-planned layout. [0,64MB) is dead by scores time -> Sc alias.
  unsigned short* Xqh   = (unsigned short*)(ws + 0);          // 16MB, dead after T
  unsigned short* Xvh   = (unsigned short*)(ws + 16 * MB);    // 16MB, dead after Vproj
  unsigned short* Xql   = (unsigned short*)(ws + 32 * MB);    // 16MB, dead after T
  unsigned short* Wkh   = (unsigned short*)(ws + 48 * MB);    // 2MB, dead after M
  unsigned short* Wkl   = (unsigned short*)(ws + 50 * MB);
  unsigned short* Wqh   = (unsigned short*)(ws + 52 * MB);
  unsigned short* Wql   = (unsigned short*)(ws + 54 * MB);
  unsigned short* MThi  = (unsigned short*)(ws + 56 * MB);    // 2MB, dead after T
  unsigned short* MTlo  = (unsigned short*)(ws + 58 * MB);
  unsigned short* Xkh   = (unsigned short*)(ws + 76 * MB);    // 16MB, live thru scores
  unsigned short* Xkl   = (unsigned short*)(ws + 92 * MB);    // 16MB
  unsigned short* Thi   = (unsigned short*)(ws + 108 * MB);   // 16MB, live thru scores
  unsigned short* Tlo   = (unsigned short*)(ws + 124 * MB);   // 16MB
  unsigned short* VT    = (unsigned short*)(ws + 140 * MB);   // 16MB, live thru PV
  unsigned short* WvT   = (unsigned short*)(ws + 156 * MB);   // 2MB, dead after Vproj
  float*          MTpart= (float*)(ws + 158 * MB);            // 16MB f32, dead after reduce
  float*          Sc    = (float*)(ws + 0);                   // 64MB alias over dead region

  // --- precision prep ---
  split_w_kernel<<<dim3(512, 1, 2), 256, 0, stream>>>(Wk, Wq, Wkh, Wkl, Wqh, Wql);
  convert_wv_kernel<<<dim3(16, 16), 256, 0, stream>>>(Wv, WvT);
  convert_x_kernel<<<dim3(4096, 1, 3), 256, 0, stream>>>(Xk, Xq, Xv, Xkh, Xkl,
                                                         Xqh, Xql, Xvh);

  // --- M^T = Wk . Wq^T, split-K over 4 256-wide K-slices, f32 partials ---
  gemm_db_kernel<3, 0, false, false><<<dim3(8, 8, 4), 256, 0, stream>>>(
      Wkh, Wkl, Wqh, Wql, 1024, 1024, 256, MTpart, nullptr, nullptr, 1024,
      256, 256, (size_t)1024 * 1024);
  reduce_mt_kernel<<<dim3(1024), 256, 0, stream>>>(MTpart, MThi, MTlo);

  // --- T = Xq . MT^T (3-term, hi+lo out) ---
  gemm_db_kernel<3, 1, false, false><<<dim3(8, 64, 1), 256, 0, stream>>>(
      Xqh, Xql, MThi, MTlo, 1024, 1024, 1024, nullptr, Thi, Tlo, 1024, 0, 0, 0);

  // --- V = Xv . Wv (plain bf16 1-term), epilogue writes VT directly ---
  gemm_db_kernel<1, 3, false, false><<<dim3(8, 64, 1), 256, 0, stream>>>(
      Xvh, nullptr, WvT, nullptr, 1024, 1024, 1024, nullptr, VT, nullptr,
      2048, 0, 0, 0);

  // --- scores = T . Xk^T (raw), packed lower-triangle tiles, f32 out ---
  gemm_db_kernel<3, 0, true, false><<<dim3(136, 1, 4), 256, 0, stream>>>(
      Thi, Tlo, Xkh, Xkl, 1024, 1024, 1024, Sc, nullptr, nullptr, 2048,
      (size_t)2048 * 1024, (size_t)2048 * 1024, (size_t)2048 * 2048);

  softmax_kernel<<<dim3(8192), 256, 0, stream>>>(Sc);

  // --- out = P . V (P bf16 pitch 4096, VT K-major), K stops at diagonal ---
  gemm_db_kernel<1, 0, false, true><<<dim3(8, 16, 4), 256, 0, stream>>>(
      (const unsigned short*)Sc, nullptr, VT, nullptr, 4096, 2048, 2048,
      out, nullptr, nullptr, 1024, (size_t)2048 * 4096, (size_t)1024 * 2048,
      (size_t)2048 * 1024);
}

// Round 10
// 187.620 us; speedup vs baseline: 1.8594x; 1.3125x over previous
//
#include <hip/hip_runtime.h>
#include <math.h>

using f32x4  = __attribute__((ext_vector_type(4))) float;
using bf16x8 = __attribute__((ext_vector_type(8))) short;
using f16x8  = __attribute__((ext_vector_type(8))) _Float16;
using u16x8  = __attribute__((ext_vector_type(8))) unsigned short;
using u16x4  = __attribute__((ext_vector_type(4))) unsigned short;

static __device__ __forceinline__ unsigned short f2bf(float f) {
  unsigned int u = __builtin_bit_cast(unsigned int, f);
  u += 0x7FFFu + ((u >> 16) & 1u);
  return (unsigned short)(u >> 16);
}
static __device__ __forceinline__ float bf2f(unsigned short h) {
  unsigned int u = ((unsigned int)h) << 16;
  return __builtin_bit_cast(float, u);
}
static __device__ __forceinline__ unsigned short f2h(float f) {
  _Float16 h = (_Float16)f;
  return __builtin_bit_cast(unsigned short, h);
}
static __device__ __forceinline__ float h2f(unsigned short u) {
  return (float)__builtin_bit_cast(_Float16, u);
}

// dtype-dispatched 16x16x32 MFMA (C/D layout is dtype-independent, m89/m121)
template <bool F16>
static __device__ __forceinline__ f32x4 mfma16(bf16x8 a, bf16x8 b, f32x4 c) {
  if constexpr (F16)
    return __builtin_amdgcn_mfma_f32_16x16x32_f16(
        __builtin_bit_cast(f16x8, a), __builtin_bit_cast(f16x8, b), c, 0, 0, 0);
  else
    return __builtin_amdgcn_mfma_f32_16x16x32_bf16(a, b, c, 0, 0, 0);
}
template <bool F16>
static __device__ __forceinline__ unsigned short cvt16(float v) {
  if constexpr (F16) return f2h(v);
  else return f2bf(v);
}

// async global->LDS, 16B per lane. LDS dest is wave-uniform base; HW appends
// lane*16.
static __device__ __forceinline__ void gll16(const void* g, void* l) {
  using GPtr = const unsigned int __attribute__((address_space(1)))*;
  using LPtr = unsigned int __attribute__((address_space(3)))*;
  __builtin_amdgcn_global_load_lds((GPtr)(unsigned long long)g,
                                   (LPtr)(unsigned)(unsigned long long)l,
                                   16, 0, 0);
}

// Stage one [128][BK] 16-bit tile (rule #21: linear LDS dest, pre-swizzled
// global source). Wave w stages rows [32w, 32w+32).
// BK=64: rows are 128B lines; slot (16B) XOR row&7.        [r3+: 0-conflict]
// BK=32: PAIRED-ROW layout — 64 lines x 128B.              [r7: 0-conflict]
// Loads issued per wave per tile: BK=64 -> 4, BK=32 -> 2.
template <int BK>
static __device__ __forceinline__ void stageT(unsigned short* sdst,
                                              const unsigned short* g,
                                              size_t ld, int k0, int wave,
                                              int lane) {
  if constexpr (BK == 64) {
    const int r = lane >> 3, c8 = lane & 7;
    const int scol = (c8 ^ r) << 3;
#pragma unroll
    for (int i = 0; i < 4; ++i)
      gll16(g + (size_t)(wave * 32 + i * 8 + r) * ld + (k0 + scol),
            sdst + wave * 2048 + i * 512);
  } else {
    const int p = lane & 7;    // physical 16B slot in line
    const int ll = lane >> 3;  // local line 0..7
#pragma unroll
    for (int i = 0; i < 2; ++i) {
      const int line = wave * 16 + i * 8 + ll;  // global line 0..63
      const int q = p ^ (line & 7);
      const int srow = 2 * line + (q >> 2);
      const int scol = (q & 3) << 3;
      gll16(g + (size_t)srow * ld + (k0 + scol), sdst + wave * 1024 + i * 512);
    }
  }
}

// Swizzled fragment read matching stageT's layout.
template <int BK>
static __device__ __forceinline__ bf16x8 fragT(const unsigned short* s,
                                               int row, int kko) {
  if constexpr (BK == 64) {
    return *(const bf16x8*)&s[row * 64 + (kko ^ ((row & 7) << 3))];
  } else {
    const int line = row >> 1;
    const int q = ((row & 1) << 2) | (kko >> 3);
    const int p = q ^ (line & 7);
    return *(const bf16x8*)&s[line * 64 + p * 8];
  }
}

// ---------------------------------------------------------------------------
// Elementwise split: W [1024x1024] f32 -> Wh/Wl bf16 (for the M GEMM).
// z: 0 = Wk, 1 = Wq.
// ---------------------------------------------------------------------------
__global__ __launch_bounds__(256) void split_w_kernel(
    const float* __restrict__ Wk, const float* __restrict__ Wq,
    unsigned short* __restrict__ Wkh, unsigned short* __restrict__ Wkl,
    unsigned short* __restrict__ Wqh, unsigned short* __restrict__ Wql) {
  const int z = blockIdx.z;
  const float* W = (z == 0) ? Wk : Wq;
  unsigned short* H = (z == 0) ? Wkh : Wqh;
  unsigned short* L = (z == 0) ? Wkl : Wql;
  const size_t base = ((size_t)blockIdx.x * 256 + threadIdx.x) * 8;
  float av[8];
  *(f32x4*)&av[0] = *(const f32x4*)&W[base];
  *(f32x4*)&av[4] = *(const f32x4*)&W[base + 4];
  u16x8 h, l;
#pragma unroll
  for (int e = 0; e < 8; ++e) {
    unsigned short hh = f2bf(av[e]);
    h[e] = hh;
    l[e] = f2bf(av[e] - bf2f(hh));
  }
  *(u16x8*)&H[base] = h;
  *(u16x8*)&L[base] = l;
}

// ---------------------------------------------------------------------------
// Wv [1024 i][1024 o] f32 -> WvT [1024 o][1024 i] f16 (transposed)
// ---------------------------------------------------------------------------
__global__ __launch_bounds__(256) void convert_wv_kernel(
    const float* __restrict__ Wv, unsigned short* __restrict__ WvT) {
  __shared__ float sW[64][65];
  const int ti = blockIdx.x * 64;
  const int tj = blockIdx.y * 64;
  const int tid = threadIdx.x;
#pragma unroll
  for (int it = 0; it < 4; ++it) {
    int idx = tid + it * 256;
    int r = idx >> 4, c = (idx & 15) << 2;
    f32x4 v = *(const f32x4*)&Wv[(size_t)(ti + r) * 1024 + tj + c];
    sW[r][c] = v[0]; sW[r][c + 1] = v[1]; sW[r][c + 2] = v[2]; sW[r][c + 3] = v[3];
  }
  __syncthreads();
#pragma unroll
  for (int it = 0; it < 4; ++it) {
    int idx = tid + it * 256;
    int ro = idx >> 4, ci = (idx & 15) << 2;
    u16x4 h;
#pragma unroll
    for (int e = 0; e < 4; ++e) h[e] = f2h(sW[ci + e][ro]);
    *(u16x4*)&WvT[(size_t)(tj + ro) * 1024 + ti + ci] = h;
  }
}

// ---------------------------------------------------------------------------
// X [8192 x 1024] f32 -> X_f16, same layout. z: 0 = keys, 1 = queries,
// 2 = values.
// ---------------------------------------------------------------------------
__global__ __launch_bounds__(256) void convert_x_kernel(
    const float* __restrict__ Xk, const float* __restrict__ Xq,
    const float* __restrict__ Xv, unsigned short* __restrict__ Xkh,
    unsigned short* __restrict__ Xqh, unsigned short* __restrict__ Xvh) {
  const int z = blockIdx.z;
  const float* X = (z == 0) ? Xk : (z == 1) ? Xq : Xv;
  unsigned short* H = (z == 0) ? Xkh : (z == 1) ? Xqh : Xvh;
  const size_t base = ((size_t)blockIdx.x * 256 + threadIdx.x) * 8;
  float av[8];
  *(f32x4*)&av[0] = *(const f32x4*)&X[base];
  *(f32x4*)&av[4] = *(const f32x4*)&X[base + 4];
  u16x8 h;
#pragma unroll
  for (int e = 0; e < 8; ++e) h[e] = f2h(av[e]);
  *(u16x8*)&H[base] = h;
}

// ---------------------------------------------------------------------------
// Unified 16-bit GEMM, deep 2-buffer counted-vmcnt pipeline (T4, r8-verified):
// prologue stages BOTH buffers; per step: vmcnt(LPS) -> barrier -> MFMA ->
// lgkmcnt(0) -> barrier -> restage for st+2. LPS: NTERMS 3 -> 8, 2 -> 6,
// 1 -> 8. NTERMS==3: BK=32 paired-row, 4 tiles/buf (64KB); NTERMS==2: BK=32,
// 3 tiles/buf (48KB); NTERMS==1: BK=64, 2 tiles/buf (64KB). XCD swizzle (T1).
// Terms: 3 = AhBh+AhBl+AlBh ; 2 = AhBh+AhBl ; 1 = AhBh.
// F16: use f16 MFMA + f16 epilogue converts (else bf16).
// EPI: 0 = f32 C ; 1 = 16b hi+lo ; 2 = 16b hi ; 3 = 16b transposed into
// VT[4][1024][2048] (fused V-transpose).
// PACKED: lid%gx is a packed lower-triangle tile index.
// PVK: K-loop ends at (bm+1)*128.
// ---------------------------------------------------------------------------
template <int NTERMS, int EPI, bool PACKED, bool PVK, bool F16>
__global__ __launch_bounds__(256, 2) void gemm_db_kernel(
    const unsigned short* __restrict__ Ah, const unsigned short* __restrict__ Al,
    const unsigned short* __restrict__ Bh, const unsigned short* __restrict__ Bl,
    size_t lda, size_t ldb, int K,
    float* __restrict__ Cf, unsigned short* __restrict__ Ch,
    unsigned short* __restrict__ Cl, size_t ldc,
    size_t abatch, size_t bbatch, size_t cbatch) {
  constexpr int BK = (NTERMS >= 2) ? 32 : 64;
  constexpr int NTILES = (NTERMS == 3) ? 4 : (NTERMS == 2) ? 3 : 2;
  constexpr int TILE = 128 * BK;  // shorts per tile
  __shared__ unsigned short smem[2][NTILES * TILE];

  // Bijective XCD-chunked swizzle over the full linearized grid (m204).
  int lid = blockIdx.x + gridDim.x * (blockIdx.y + gridDim.y * blockIdx.z);
  {
    const int n = gridDim.x * gridDim.y * gridDim.z;
    const int q = n >> 3, r = n & 7, x = lid & 7, k = lid >> 3;
    lid = (x < r ? x * (q + 1) : r * (q + 1) + (x - r) * q) + k;
  }
  int bm, bn, b;
  if constexpr (PACKED) {
    const int t = lid % gridDim.x;
    b = lid / gridDim.x;
    bm = (int)((sqrtf(8.f * (float)t + 1.f) - 1.f) * 0.5f);
    while ((bm + 1) * (bm + 2) / 2 <= t) ++bm;
    while (bm * (bm + 1) / 2 > t) --bm;
    bn = t - bm * (bm + 1) / 2;
  } else {
    bn = lid % gridDim.x;
    const int tmp = lid / gridDim.x;
    bm = tmp % gridDim.y;
    b = tmp / gridDim.y;
  }
  const int tid = threadIdx.x, lane = tid & 63, wave = tid >> 6;
  const unsigned short* gA = Ah + abatch * b + (size_t)(bm * 128) * lda;
  const unsigned short* gB = Bh + bbatch * b + (size_t)(bn * 128) * ldb;
  const unsigned short* gAl2 =
      (NTERMS == 3) ? Al + abatch * b + (size_t)(bm * 128) * lda : nullptr;
  const unsigned short* gBl2 =
      (NTERMS >= 2) ? Bl + bbatch * b + (size_t)(bn * 128) * ldb : nullptr;
  const int kend = PVK ? (bm + 1) * 128 : K;
  const int nsteps = kend / BK;
  f32x4 acc[4][4] = {};
  const int wr = (wave >> 1) << 6, wc = (wave & 1) << 6;
  const int frow = lane & 15, koff = (lane >> 4) << 3;

  auto stage_all = [&](unsigned short* buf, int k0) {
    stageT<BK>(buf, gA, lda, k0, wave, lane);
    stageT<BK>(buf + TILE, gB, ldb, k0, wave, lane);
    if constexpr (NTERMS >= 2) stageT<BK>(buf + 2 * TILE, gBl2, ldb, k0, wave, lane);
    if constexpr (NTERMS == 3) stageT<BK>(buf + 3 * TILE, gAl2, lda, k0, wave, lane);
  };

  stage_all(smem[0], 0);
  if (nsteps > 1) stage_all(smem[1], BK);
  int cur = 0;
  for (int st = 0; st < nsteps; ++st) {
    if (st + 1 < nsteps) {
      if constexpr (NTERMS == 2)
        asm volatile("s_waitcnt vmcnt(6)" ::: "memory");
      else
        asm volatile("s_waitcnt vmcnt(8)" ::: "memory");
    } else {
      asm volatile("s_waitcnt vmcnt(0)" ::: "memory");
    }
    __builtin_amdgcn_sched_barrier(0);
    __builtin_amdgcn_s_barrier();  // buf[cur] fully in LDS (all waves)
    __builtin_amdgcn_sched_barrier(0);
    const unsigned short* sA = smem[cur];
    const unsigned short* sB = smem[cur] + TILE;
    if constexpr (NTERMS >= 2) {
      const unsigned short* sBl = smem[cur] + 2 * TILE;
      const unsigned short* sAl = smem[cur] + 3 * TILE;  // NTERMS==3 only
      bf16x8 fBh[4], fBl[4];
#pragma unroll
      for (int j = 0; j < 4; ++j) {
        fBh[j] = fragT<BK>(sB, wc + j * 16 + frow, koff);
        fBl[j] = fragT<BK>(sBl, wc + j * 16 + frow, koff);
      }
#pragma unroll
      for (int i = 0; i < 4; ++i) {
        const bf16x8 ah = fragT<BK>(sA, wr + i * 16 + frow, koff);
        bf16x8 al = {};
        if constexpr (NTERMS == 3) al = fragT<BK>(sAl, wr + i * 16 + frow, koff);
#pragma unroll
        for (int j = 0; j < 4; ++j) {
          acc[i][j] = mfma16<F16>(ah, fBh[j], acc[i][j]);
          acc[i][j] = mfma16<F16>(ah, fBl[j], acc[i][j]);
          if constexpr (NTERMS == 3)
            acc[i][j] = mfma16<F16>(al, fBh[j], acc[i][j]);
        }
      }
    } else {
#pragma unroll
      for (int kk = 0; kk < 64; kk += 32) {
        const int kko = kk + koff;
        bf16x8 fBh[4];
#pragma unroll
        for (int j = 0; j < 4; ++j) fBh[j] = fragT<BK>(sB, wc + j * 16 + frow, kko);
#pragma unroll
        for (int i = 0; i < 4; ++i) {
          const bf16x8 ah = fragT<BK>(sA, wr + i * 16 + frow, kko);
#pragma unroll
          for (int j = 0; j < 4; ++j)
            acc[i][j] = mfma16<F16>(ah, fBh[j], acc[i][j]);
        }
      }
    }
    asm volatile("s_waitcnt lgkmcnt(0)" ::: "memory");
    __builtin_amdgcn_sched_barrier(0);
    __builtin_amdgcn_s_barrier();  // all waves done reading buf[cur]
    __builtin_amdgcn_sched_barrier(0);
    if (st + 2 < nsteps) stage_all(smem[cur], (st + 2) * BK);
    cur ^= 1;
  }

  const int erow = bm * 128 + wr + ((lane >> 4) << 2);
  const int ecol = bn * 128 + wc + frow;
  if constexpr (EPI == 0) {
    float* C = Cf + cbatch * b;
#pragma unroll
    for (int i = 0; i < 4; ++i)
#pragma unroll
      for (int j = 0; j < 4; ++j)
#pragma unroll
        for (int e = 0; e < 4; ++e)
          C[(size_t)(erow + i * 16 + e) * ldc + (ecol + j * 16)] = acc[i][j][e];
  } else if constexpr (EPI == 3) {
    // Fused V-transpose: Ch is VT[4][1024 o][2048 s].
#pragma unroll
    for (int i = 0; i < 4; ++i)
#pragma unroll
      for (int j = 0; j < 4; ++j) {
        const int s = erow + i * 16;
        const int o = ecol + j * 16;
        u16x4 v;
#pragma unroll
        for (int e = 0; e < 4; ++e) v[e] = cvt16<F16>(acc[i][j][e]);
        *(u16x4*)&Ch[((size_t)(s >> 11) * 1024 + o) * 2048 + (s & 2047)] = v;
      }
  } else {
    unsigned short* Cho = Ch + cbatch * b;
    unsigned short* Clo = (EPI == 1) ? Cl + cbatch * b : nullptr;
#pragma unroll
    for (int i = 0; i < 4; ++i)
#pragma unroll
      for (int j = 0; j < 4; ++j)
#pragma unroll
        for (int e = 0; e < 4; ++e) {
          size_t off = (size_t)(erow + i * 16 + e) * ldc + (ecol + j * 16);
          float v = acc[i][j][e];
          unsigned short hh = cvt16<F16>(v);
          Cho[off] = hh;
          if constexpr (EPI == 1) Clo[off] = f2bf(v - bf2f(hh));
        }
  }
}

// ---------------------------------------------------------------------------
// Sum 4 split-K partials of MT (f32) -> MTh/MTl **f16** split. [1024x1024]
// f16 split error ~2^-22 relative — M side is effectively exact.
// ---------------------------------------------------------------------------
__global__ __launch_bounds__(256) void reduce_mt_kernel(
    const float* __restrict__ P, unsigned short* __restrict__ H,
    unsigned short* __restrict__ L) {
  const size_t base = ((size_t)blockIdx.x * 256 + threadIdx.x) * 4;
  f32x4 s = *(const f32x4*)&P[base];
#pragma unroll
  for (int z = 1; z < 4; ++z) {
    f32x4 v = *(const f32x4*)&P[(size_t)z * 1048576 + base];
    s[0] += v[0]; s[1] += v[1]; s[2] += v[2]; s[3] += v[3];
  }
  u16x4 h, l;
#pragma unroll
  for (int e = 0; e < 4; ++e) {
    unsigned short hh = f2h(s[e]);
    h[e] = hh;
    l[e] = f2h(s[e] - h2f(hh));
  }
  *(u16x4*)&H[base] = h;
  *(u16x4*)&L[base] = l;
}

// ---------------------------------------------------------------------------
// Row softmax with causal mask + 1/sqrt(d) scale. Writes **f16** P in-place
// over the f32 scores buffer. Safe: reads complete before first barrier.
// ---------------------------------------------------------------------------
__global__ __launch_bounds__(256) void softmax_kernel(float* __restrict__ Sc) {
  const int row = blockIdx.x;  // b*2048 + q
  const int q = row & 2047;
  const int tid = threadIdx.x, lane = tid & 63, wave = tid >> 6;
  float* srow = Sc + (size_t)row * 2048;
  unsigned short* prow = (unsigned short*)srow;
  const int k0 = tid * 4, k1 = 1024 + tid * 4;
  f32x4 v0 = {}, v1 = {};
  if (k0 <= q) v0 = *(const f32x4*)(srow + k0);
  if (k1 <= q) v1 = *(const f32x4*)(srow + k1);
  float m = -3.0e38f;
#pragma unroll
  for (int e = 0; e < 4; ++e) {
    if (k0 + e <= q) m = fmaxf(m, v0[e]);
    if (k1 + e <= q) m = fmaxf(m, v1[e]);
  }
#pragma unroll
  for (int o = 32; o; o >>= 1) m = fmaxf(m, __shfl_xor(m, o));
  __shared__ float redm[4], reds[4];
  if (lane == 0) redm[wave] = m;
  __syncthreads();
  m = fmaxf(fmaxf(redm[0], redm[1]), fmaxf(redm[2], redm[3]));
  const float scale = 0.03125f;  // 1/sqrt(1024)
  float p[8];
  float s = 0.f;
#pragma unroll
  for (int e = 0; e < 4; ++e) {
    p[e] = (k0 + e <= q) ? __expf((v0[e] - m) * scale) : 0.f;
    p[4 + e] = (k1 + e <= q) ? __expf((v1[e] - m) * scale) : 0.f;
    s += p[e] + p[4 + e];
  }
#pragma unroll
  for (int o = 32; o; o >>= 1) s += __shfl_xor(s, o);
  if (lane == 0) reds[wave] = s;
  __syncthreads();
  s = reds[0] + reds[1] + reds[2] + reds[3];
  const float inv = 1.0f / s;
  u16x4 o0, o1;
#pragma unroll
  for (int e = 0; e < 4; ++e) {
    o0[e] = f2h(p[e] * inv);
    o1[e] = f2h(p[4 + e] * inv);
  }
  *(u16x4*)&prow[k0] = o0;
  *(u16x4*)&prow[k1] = o1;
}

// ---------------------------------------------------------------------------
extern "C" void kernel_launch(void* const* d_in, const int* in_sizes, int n_in,
                              void* d_out, int out_size, void* d_ws, size_t ws_size,
                              hipStream_t stream) {
  const float* Xk = (const float*)d_in[0];
  const float* Xv = (const float*)d_in[1];
  const float* Xq = (const float*)d_in[2];
  const float* Wk = (const float*)d_in[3];
  const float* Wv = (const float*)d_in[4];
  const float* Wq = (const float*)d_in[5];
  float* out = (float*)d_out;

  char* ws = (char*)d_ws;
  const size_t MB = 1024ull * 1024;
  // Liveness: everything in [0,64MB) is dead before scores -> Sc alias.
  unsigned short* Xqh   = (unsigned short*)(ws + 0);          // 16MB f16, dead after T
  unsigned short* Xvh   = (unsigned short*)(ws + 16 * MB);    // 16MB f16, dead after V
  unsigned short* Wkh   = (unsigned short*)(ws + 32 * MB);    // 2MB bf16, dead after M
  unsigned short* Wkl   = (unsigned short*)(ws + 34 * MB);
  unsigned short* Wqh   = (unsigned short*)(ws + 36 * MB);
  unsigned short* Wql   = (unsigned short*)(ws + 38 * MB);
  unsigned short* MTh   = (unsigned short*)(ws + 40 * MB);    // 2MB f16, dead after T
  unsigned short* MTl   = (unsigned short*)(ws + 42 * MB);
  unsigned short* WvT   = (unsigned short*)(ws + 44 * MB);    // 2MB f16, dead after V
  float*          MTpart= (float*)(ws + 46 * MB);             // 16MB f32, dead after reduce
  unsigned short* Xkh   = (unsigned short*)(ws + 64 * MB);    // 16MB f16, live thru scores
  unsigned short* Th    = (unsigned short*)(ws + 80 * MB);    // 16MB f16, live thru scores
  unsigned short* VT    = (unsigned short*)(ws + 96 * MB);    // 16MB f16, live thru PV
  float*          Sc    = (float*)(ws + 0);                   // 64MB alias over dead region

  // --- precision prep ---
  split_w_kernel<<<dim3(512, 1, 2), 256, 0, stream>>>(Wk, Wq, Wkh, Wkl, Wqh, Wql);
  convert_wv_kernel<<<dim3(16, 16), 256, 0, stream>>>(Wv, WvT);
  convert_x_kernel<<<dim3(4096, 1, 3), 256, 0, stream>>>(Xk, Xq, Xv, Xkh, Xqh, Xvh);

  // --- M^T = Wk . Wq^T (3-term bf16 split), split-K over 4 K-slices ---
  gemm_db_kernel<3, 0, false, false, false><<<dim3(8, 8, 4), 256, 0, stream>>>(
      Wkh, Wkl, Wqh, Wql, 1024, 1024, 256, MTpart, nullptr, nullptr, 1024,
      256, 256, (size_t)1024 * 1024);
  reduce_mt_kernel<<<dim3(1024), 256, 0, stream>>>(MTpart, MTh, MTl);

  // --- T = Xq_f16 . (MTh + MTl)^T (2-term f16, f16 out) ---
  gemm_db_kernel<2, 2, false, false, true><<<dim3(8, 64, 1), 256, 0, stream>>>(
      Xqh, nullptr, MTh, MTl, 1024, 1024, 1024, nullptr, Th, nullptr,
      1024, 0, 0, 0);

  // --- V = Xv . Wv (1-term f16), epilogue writes VT (f16) directly ---
  gemm_db_kernel<1, 3, false, false, true><<<dim3(8, 64, 1), 256, 0, stream>>>(
      Xvh, nullptr, WvT, nullptr, 1024, 1024, 1024, nullptr, VT, nullptr,
      2048, 0, 0, 0);

  // --- scores = T_f16 . Xk_f16^T (1-term f16!), packed lower-triangle ---
  gemm_db_kernel<1, 0, true, false, true><<<dim3(136, 1, 4), 256, 0, stream>>>(
      Th, nullptr, Xkh, nullptr, 1024, 1024, 1024, Sc, nullptr, nullptr, 2048,
      (size_t)2048 * 1024, (size_t)2048 * 1024, (size_t)2048 * 2048);

  softmax_kernel<<<dim3(8192), 256, 0, stream>>>(Sc);

  // --- out = P_f16 . V (f16), P pitch 4096, VT K-major, K stops at diag ---
  gemm_db_kernel<1, 0, false, true, true><<<dim3(8, 16, 4), 256, 0, stream>>>(
      (const unsigned short*)Sc, nullptr, VT, nullptr, 4096, 2048, 2048,
      out, nullptr, nullptr, 1024, (size_t)2048 * 4096, (size_t)1024 * 2048,
      (size_t)2048 * 1024);
}

// Round 11
// 169.388 us; speedup vs baseline: 2.0595x; 1.1076x over previous
//
#include <hip/hip_runtime.h>
#include <math.h>

using f32x4  = __attribute__((ext_vector_type(4))) float;
using bf16x8 = __attribute__((ext_vector_type(8))) short;
using f16x8  = __attribute__((ext_vector_type(8))) _Float16;
using u16x8  = __attribute__((ext_vector_type(8))) unsigned short;
using u16x4  = __attribute__((ext_vector_type(4))) unsigned short;

static __device__ __forceinline__ unsigned short f2bf(float f) {
  unsigned int u = __builtin_bit_cast(unsigned int, f);
  u += 0x7FFFu + ((u >> 16) & 1u);
  return (unsigned short)(u >> 16);
}
static __device__ __forceinline__ float bf2f(unsigned short h) {
  unsigned int u = ((unsigned int)h) << 16;
  return __builtin_bit_cast(float, u);
}
static __device__ __forceinline__ unsigned short f2h(float f) {
  _Float16 h = (_Float16)f;
  return __builtin_bit_cast(unsigned short, h);
}
static __device__ __forceinline__ float h2f(unsigned short u) {
  return (float)__builtin_bit_cast(_Float16, u);
}

// dtype-dispatched 16x16x32 MFMA (C/D layout is dtype-independent, m89/m121)
template <bool F16>
static __device__ __forceinline__ f32x4 mfma16(bf16x8 a, bf16x8 b, f32x4 c) {
  if constexpr (F16)
    return __builtin_amdgcn_mfma_f32_16x16x32_f16(
        __builtin_bit_cast(f16x8, a), __builtin_bit_cast(f16x8, b), c, 0, 0, 0);
  else
    return __builtin_amdgcn_mfma_f32_16x16x32_bf16(a, b, c, 0, 0, 0);
}
template <bool F16>
static __device__ __forceinline__ unsigned short cvt16(float v) {
  if constexpr (F16) return f2h(v);
  else return f2bf(v);
}

// async global->LDS, 16B per lane. LDS dest is wave-uniform base; HW appends
// lane*16.
static __device__ __forceinline__ void gll16(const void* g, void* l) {
  using GPtr = const unsigned int __attribute__((address_space(1)))*;
  using LPtr = unsigned int __attribute__((address_space(3)))*;
  __builtin_amdgcn_global_load_lds((GPtr)(unsigned long long)g,
                                   (LPtr)(unsigned)(unsigned long long)l,
                                   16, 0, 0);
}

// Stage one [128][BK] 16-bit tile (rule #21: linear LDS dest, pre-swizzled
// global source). Wave w stages rows [32w, 32w+32).
// BK=64: rows are 128B lines; slot (16B) XOR row&7.        [r3+: 0-conflict]
// BK=32: PAIRED-ROW layout — 64 lines x 128B.              [r7: 0-conflict]
// Loads issued per wave per tile: BK=64 -> 4, BK=32 -> 2.
template <int BK>
static __device__ __forceinline__ void stageT(unsigned short* sdst,
                                              const unsigned short* g,
                                              size_t ld, int k0, int wave,
                                              int lane) {
  if constexpr (BK == 64) {
    const int r = lane >> 3, c8 = lane & 7;
    const int scol = (c8 ^ r) << 3;
#pragma unroll
    for (int i = 0; i < 4; ++i)
      gll16(g + (size_t)(wave * 32 + i * 8 + r) * ld + (k0 + scol),
            sdst + wave * 2048 + i * 512);
  } else {
    const int p = lane & 7;    // physical 16B slot in line
    const int ll = lane >> 3;  // local line 0..7
#pragma unroll
    for (int i = 0; i < 2; ++i) {
      const int line = wave * 16 + i * 8 + ll;  // global line 0..63
      const int q = p ^ (line & 7);
      const int srow = 2 * line + (q >> 2);
      const int scol = (q & 3) << 3;
      gll16(g + (size_t)srow * ld + (k0 + scol), sdst + wave * 1024 + i * 512);
    }
  }
}

// Swizzled fragment read matching stageT's layout.
template <int BK>
static __device__ __forceinline__ bf16x8 fragT(const unsigned short* s,
                                               int row, int kko) {
  if constexpr (BK == 64) {
    return *(const bf16x8*)&s[row * 64 + (kko ^ ((row & 7) << 3))];
  } else {
    const int line = row >> 1;
    const int q = ((row & 1) << 2) | (kko >> 3);
    const int p = q ^ (line & 7);
    return *(const bf16x8*)&s[line * 64 + p * 8];
  }
}

// ---------------------------------------------------------------------------
// Elementwise split: W [1024x1024] f32 -> Wh/Wl bf16 (for the M GEMM).
// z: 0 = Wk, 1 = Wq.
// ---------------------------------------------------------------------------
__global__ __launch_bounds__(256) void split_w_kernel(
    const float* __restrict__ Wk, const float* __restrict__ Wq,
    unsigned short* __restrict__ Wkh, unsigned short* __restrict__ Wkl,
    unsigned short* __restrict__ Wqh, unsigned short* __restrict__ Wql) {
  const int z = blockIdx.z;
  const float* W = (z == 0) ? Wk : Wq;
  unsigned short* H = (z == 0) ? Wkh : Wqh;
  unsigned short* L = (z == 0) ? Wkl : Wql;
  const size_t base = ((size_t)blockIdx.x * 256 + threadIdx.x) * 8;
  float av[8];
  *(f32x4*)&av[0] = *(const f32x4*)&W[base];
  *(f32x4*)&av[4] = *(const f32x4*)&W[base + 4];
  u16x8 h, l;
#pragma unroll
  for (int e = 0; e < 8; ++e) {
    unsigned short hh = f2bf(av[e]);
    h[e] = hh;
    l[e] = f2bf(av[e] - bf2f(hh));
  }
  *(u16x8*)&H[base] = h;
  *(u16x8*)&L[base] = l;
}

// ---------------------------------------------------------------------------
// Wv [1024 i][1024 o] f32 -> WvT [1024 o][1024 i] f16 (transposed)
// ---------------------------------------------------------------------------
__global__ __launch_bounds__(256) void convert_wv_kernel(
    const float* __restrict__ Wv, unsigned short* __restrict__ WvT) {
  __shared__ float sW[64][65];
  const int ti = blockIdx.x * 64;
  const int tj = blockIdx.y * 64;
  const int tid = threadIdx.x;
#pragma unroll
  for (int it = 0; it < 4; ++it) {
    int idx = tid + it * 256;
    int r = idx >> 4, c = (idx & 15) << 2;
    f32x4 v = *(const f32x4*)&Wv[(size_t)(ti + r) * 1024 + tj + c];
    sW[r][c] = v[0]; sW[r][c + 1] = v[1]; sW[r][c + 2] = v[2]; sW[r][c + 3] = v[3];
  }
  __syncthreads();
#pragma unroll
  for (int it = 0; it < 4; ++it) {
    int idx = tid + it * 256;
    int ro = idx >> 4, ci = (idx & 15) << 2;
    u16x4 h;
#pragma unroll
    for (int e = 0; e < 4; ++e) h[e] = f2h(sW[ci + e][ro]);
    *(u16x4*)&WvT[(size_t)(tj + ro) * 1024 + ti + ci] = h;
  }
}

// ---------------------------------------------------------------------------
// X [8192 x 1024] f32 -> X_f16, same layout, 16 elems/thread.
// z: 0 = keys, 1 = queries, 2 = values.
// ---------------------------------------------------------------------------
__global__ __launch_bounds__(256) void convert_x_kernel(
    const float* __restrict__ Xk, const float* __restrict__ Xq,
    const float* __restrict__ Xv, unsigned short* __restrict__ Xkh,
    unsigned short* __restrict__ Xqh, unsigned short* __restrict__ Xvh) {
  const int z = blockIdx.z;
  const float* X = (z == 0) ? Xk : (z == 1) ? Xq : Xv;
  unsigned short* H = (z == 0) ? Xkh : (z == 1) ? Xqh : Xvh;
  const size_t base = ((size_t)blockIdx.x * 256 + threadIdx.x) * 16;
  float av[16];
  *(f32x4*)&av[0]  = *(const f32x4*)&X[base];
  *(f32x4*)&av[4]  = *(const f32x4*)&X[base + 4];
  *(f32x4*)&av[8]  = *(const f32x4*)&X[base + 8];
  *(f32x4*)&av[12] = *(const f32x4*)&X[base + 12];
  u16x8 h0, h1;
#pragma unroll
  for (int e = 0; e < 8; ++e) {
    h0[e] = f2h(av[e]);
    h1[e] = f2h(av[8 + e]);
  }
  *(u16x8*)&H[base] = h0;
  *(u16x8*)&H[base + 8] = h1;
}

// ---------------------------------------------------------------------------
// Unified 16-bit GEMM, deep 2-buffer counted-vmcnt pipeline (T4, r8-verified):
// prologue stages BOTH buffers; per step: vmcnt(LPS) -> barrier -> MFMA ->
// lgkmcnt(0) -> barrier -> restage for st+2. LPS: NTERMS 3 -> 8, 2 -> 6,
// 1 -> 8. NTERMS==3: BK=32 paired-row, 4 tiles/buf (64KB); NTERMS==2: BK=32,
// 3 tiles/buf (48KB); NTERMS==1: BK=64, 2 tiles/buf (64KB). XCD swizzle (T1).
// Terms: 3 = AhBh+AhBl+AlBh ; 2 = AhBh+AhBl ; 1 = AhBh.
// F16: use f16 MFMA + f16 epilogue converts (else bf16).
// EPI: 0 = f32 C ; 1 = 16b hi+lo ; 2 = 16b hi ; 3 = 16b transposed into
// VT[4][1024][2048] (fused V-transpose).
// PACKED: lid%gx is a packed lower-triangle tile index.
// PVK: K-loop ends at (bm+1)*128; bm decode is REVERSED so heavy tiles
// dispatch first (light diagonal blocks pack the tail).
// ---------------------------------------------------------------------------
template <int NTERMS, int EPI, bool PACKED, bool PVK, bool F16>
__global__ __launch_bounds__(256, 2) void gemm_db_kernel(
    const unsigned short* __restrict__ Ah, const unsigned short* __restrict__ Al,
    const unsigned short* __restrict__ Bh, const unsigned short* __restrict__ Bl,
    size_t lda, size_t ldb, int K,
    float* __restrict__ Cf, unsigned short* __restrict__ Ch,
    unsigned short* __restrict__ Cl, size_t ldc,
    size_t abatch, size_t bbatch, size_t cbatch) {
  constexpr int BK = (NTERMS >= 2) ? 32 : 64;
  constexpr int NTILES = (NTERMS == 3) ? 4 : (NTERMS == 2) ? 3 : 2;
  constexpr int TILE = 128 * BK;  // shorts per tile
  __shared__ unsigned short smem[2][NTILES * TILE];

  // Bijective XCD-chunked swizzle over the full linearized grid (m204).
  int lid = blockIdx.x + gridDim.x * (blockIdx.y + gridDim.y * blockIdx.z);
  {
    const int n = gridDim.x * gridDim.y * gridDim.z;
    const int q = n >> 3, r = n & 7, x = lid & 7, k = lid >> 3;
    lid = (x < r ? x * (q + 1) : r * (q + 1) + (x - r) * q) + k;
  }
  int bm, bn, b;
  if constexpr (PACKED) {
    const int t = lid % gridDim.x;
    b = lid / gridDim.x;
    bm = (int)((sqrtf(8.f * (float)t + 1.f) - 1.f) * 0.5f);
    while ((bm + 1) * (bm + 2) / 2 <= t) ++bm;
    while (bm * (bm + 1) / 2 > t) --bm;
    bn = t - bm * (bm + 1) / 2;
  } else {
    bn = lid % gridDim.x;
    const int tmp = lid / gridDim.x;
    bm = tmp % gridDim.y;
    b = tmp / gridDim.y;
    if constexpr (PVK) bm = (int)gridDim.y - 1 - bm;  // heavy tiles first
  }
  const int tid = threadIdx.x, lane = tid & 63, wave = tid >> 6;
  const unsigned short* gA = Ah + abatch * b + (size_t)(bm * 128) * lda;
  const unsigned short* gB = Bh + bbatch * b + (size_t)(bn * 128) * ldb;
  const unsigned short* gAl2 =
      (NTERMS == 3) ? Al + abatch * b + (size_t)(bm * 128) * lda : nullptr;
  const unsigned short* gBl2 =
      (NTERMS >= 2) ? Bl + bbatch * b + (size_t)(bn * 128) * ldb : nullptr;
  const int kend = PVK ? (bm + 1) * 128 : K;
  const int nsteps = kend / BK;
  f32x4 acc[4][4] = {};
  const int wr = (wave >> 1) << 6, wc = (wave & 1) << 6;
  const int frow = lane & 15, koff = (lane >> 4) << 3;

  auto stage_all = [&](unsigned short* buf, int k0) {
    stageT<BK>(buf, gA, lda, k0, wave, lane);
    stageT<BK>(buf + TILE, gB, ldb, k0, wave, lane);
    if constexpr (NTERMS >= 2) stageT<BK>(buf + 2 * TILE, gBl2, ldb, k0, wave, lane);
    if constexpr (NTERMS == 3) stageT<BK>(buf + 3 * TILE, gAl2, lda, k0, wave, lane);
  };

  stage_all(smem[0], 0);
  if (nsteps > 1) stage_all(smem[1], BK);
  int cur = 0;
  for (int st = 0; st < nsteps; ++st) {
    if (st + 1 < nsteps) {
      if constexpr (NTERMS == 2)
        asm volatile("s_waitcnt vmcnt(6)" ::: "memory");
      else
        asm volatile("s_waitcnt vmcnt(8)" ::: "memory");
    } else {
      asm volatile("s_waitcnt vmcnt(0)" ::: "memory");
    }
    __builtin_amdgcn_sched_barrier(0);
    __builtin_amdgcn_s_barrier();  // buf[cur] fully in LDS (all waves)
    __builtin_amdgcn_sched_barrier(0);
    const unsigned short* sA = smem[cur];
    const unsigned short* sB = smem[cur] + TILE;
    if constexpr (NTERMS >= 2) {
      const unsigned short* sBl = smem[cur] + 2 * TILE;
      const unsigned short* sAl = smem[cur] + 3 * TILE;  // NTERMS==3 only
      bf16x8 fBh[4], fBl[4];
#pragma unroll
      for (int j = 0; j < 4; ++j) {
        fBh[j] = fragT<BK>(sB, wc + j * 16 + frow, koff);
        fBl[j] = fragT<BK>(sBl, wc + j * 16 + frow, koff);
      }
#pragma unroll
      for (int i = 0; i < 4; ++i) {
        const bf16x8 ah = fragT<BK>(sA, wr + i * 16 + frow, koff);
        bf16x8 al = {};
        if constexpr (NTERMS == 3) al = fragT<BK>(sAl, wr + i * 16 + frow, koff);
#pragma unroll
        for (int j = 0; j < 4; ++j) {
          acc[i][j] = mfma16<F16>(ah, fBh[j], acc[i][j]);
          acc[i][j] = mfma16<F16>(ah, fBl[j], acc[i][j]);
          if constexpr (NTERMS == 3)
            acc[i][j] = mfma16<F16>(al, fBh[j], acc[i][j]);
        }
      }
    } else {
#pragma unroll
      for (int kk = 0; kk < 64; kk += 32) {
        const int kko = kk + koff;
        bf16x8 fBh[4];
#pragma unroll
        for (int j = 0; j < 4; ++j) fBh[j] = fragT<BK>(sB, wc + j * 16 + frow, kko);
#pragma unroll
        for (int i = 0; i < 4; ++i) {
          const bf16x8 ah = fragT<BK>(sA, wr + i * 16 + frow, kko);
#pragma unroll
          for (int j = 0; j < 4; ++j)
            acc[i][j] = mfma16<F16>(ah, fBh[j], acc[i][j]);
        }
      }
    }
    asm volatile("s_waitcnt lgkmcnt(0)" ::: "memory");
    __builtin_amdgcn_sched_barrier(0);
    __builtin_amdgcn_s_barrier();  // all waves done reading buf[cur]
    __builtin_amdgcn_sched_barrier(0);
    if (st + 2 < nsteps) stage_all(smem[cur], (st + 2) * BK);
    cur ^= 1;
  }

  const int erow = bm * 128 + wr + ((lane >> 4) << 2);
  const int ecol = bn * 128 + wc + frow;
  if constexpr (EPI == 0) {
    float* C = Cf + cbatch * b;
#pragma unroll
    for (int i = 0; i < 4; ++i)
#pragma unroll
      for (int j = 0; j < 4; ++j)
#pragma unroll
        for (int e = 0; e < 4; ++e)
          C[(size_t)(erow + i * 16 + e) * ldc + (ecol + j * 16)] = acc[i][j][e];
  } else if constexpr (EPI == 3) {
    // Fused V-transpose: Ch is VT[4][1024 o][2048 s].
#pragma unroll
    for (int i = 0; i < 4; ++i)
#pragma unroll
      for (int j = 0; j < 4; ++j) {
        const int s = erow + i * 16;
        const int o = ecol + j * 16;
        u16x4 v;
#pragma unroll
        for (int e = 0; e < 4; ++e) v[e] = cvt16<F16>(acc[i][j][e]);
        *(u16x4*)&Ch[((size_t)(s >> 11) * 1024 + o) * 2048 + (s & 2047)] = v;
      }
  } else {
    unsigned short* Cho = Ch + cbatch * b;
    unsigned short* Clo = (EPI == 1) ? Cl + cbatch * b : nullptr;
#pragma unroll
    for (int i = 0; i < 4; ++i)
#pragma unroll
      for (int j = 0; j < 4; ++j)
#pragma unroll
        for (int e = 0; e < 4; ++e) {
          size_t off = (size_t)(erow + i * 16 + e) * ldc + (ecol + j * 16);
          float v = acc[i][j][e];
          unsigned short hh = cvt16<F16>(v);
          Cho[off] = hh;
          if constexpr (EPI == 1) Clo[off] = f2bf(v - bf2f(hh));
        }
  }
}

// ---------------------------------------------------------------------------
// Sum 4 split-K partials of MT (f32) -> MT plain f16. [1024x1024]
// (f16 rounding of M adds ~3e-3 scaled-logit error via T — negligible.)
// ---------------------------------------------------------------------------
__global__ __launch_bounds__(256) void reduce_mt_kernel(
    const float* __restrict__ P, unsigned short* __restrict__ H) {
  const size_t base = ((size_t)blockIdx.x * 256 + threadIdx.x) * 4;
  f32x4 s = *(const f32x4*)&P[base];
#pragma unroll
  for (int z = 1; z < 4; ++z) {
    f32x4 v = *(const f32x4*)&P[(size_t)z * 1048576 + base];
    s[0] += v[0]; s[1] += v[1]; s[2] += v[2]; s[3] += v[3];
  }
  u16x4 h;
#pragma unroll
  for (int e = 0; e < 4; ++e) h[e] = f2h(s[e]);
  *(u16x4*)&H[base] = h;
}

// ---------------------------------------------------------------------------
// Row softmax with causal mask + 1/sqrt(d) scale. Writes f16 P in-place
// over the f32 scores buffer. Safe: reads complete before first barrier.
// ---------------------------------------------------------------------------
__global__ __launch_bounds__(256) void softmax_kernel(float* __restrict__ Sc) {
  const int row = blockIdx.x;  // b*2048 + q
  const int q = row & 2047;
  const int tid = threadIdx.x, lane = tid & 63, wave = tid >> 6;
  float* srow = Sc + (size_t)row * 2048;
  unsigned short* prow = (unsigned short*)srow;
  const int k0 = tid * 4, k1 = 1024 + tid * 4;
  f32x4 v0 = {}, v1 = {};
  if (k0 <= q) v0 = *(const f32x4*)(srow + k0);
  if (k1 <= q) v1 = *(const f32x4*)(srow + k1);
  float m = -3.0e38f;
#pragma unroll
  for (int e = 0; e < 4; ++e) {
    if (k0 + e <= q) m = fmaxf(m, v0[e]);
    if (k1 + e <= q) m = fmaxf(m, v1[e]);
  }
#pragma unroll
  for (int o = 32; o; o >>= 1) m = fmaxf(m, __shfl_xor(m, o));
  __shared__ float redm[4], reds[4];
  if (lane == 0) redm[wave] = m;
  __syncthreads();
  m = fmaxf(fmaxf(redm[0], redm[1]), fmaxf(redm[2], redm[3]));
  const float scale = 0.03125f;  // 1/sqrt(1024)
  float p[8];
  float s = 0.f;
#pragma unroll
  for (int e = 0; e < 4; ++e) {
    p[e] = (k0 + e <= q) ? __expf((v0[e] - m) * scale) : 0.f;
    p[4 + e] = (k1 + e <= q) ? __expf((v1[e] - m) * scale) : 0.f;
    s += p[e] + p[4 + e];
  }
#pragma unroll
  for (int o = 32; o; o >>= 1) s += __shfl_xor(s, o);
  if (lane == 0) reds[wave] = s;
  __syncthreads();
  s = reds[0] + reds[1] + reds[2] + reds[3];
  const float inv = 1.0f / s;
  u16x4 o0, o1;
#pragma unroll
  for (int e = 0; e < 4; ++e) {
    o0[e] = f2h(p[e] * inv);
    o1[e] = f2h(p[4 + e] * inv);
  }
  *(u16x4*)&prow[k0] = o0;
  *(u16x4*)&prow[k1] = o1;
}

// ---------------------------------------------------------------------------
extern "C" void kernel_launch(void* const* d_in, const int* in_sizes, int n_in,
                              void* d_out, int out_size, void* d_ws, size_t ws_size,
                              hipStream_t stream) {
  const float* Xk = (const float*)d_in[0];
  const float* Xv = (const float*)d_in[1];
  const float* Xq = (const float*)d_in[2];
  const float* Wk = (const float*)d_in[3];
  const float* Wv = (const float*)d_in[4];
  const float* Wq = (const float*)d_in[5];
  float* out = (float*)d_out;

  char* ws = (char*)d_ws;
  const size_t MB = 1024ull * 1024;
  // Liveness: everything in [0,64MB) is dead before scores -> Sc alias.
  unsigned short* Xqh   = (unsigned short*)(ws + 0);          // 16MB f16, dead after T
  unsigned short* Xvh   = (unsigned short*)(ws + 16 * MB);    // 16MB f16, dead after V
  unsigned short* Wkh   = (unsigned short*)(ws + 32 * MB);    // 2MB bf16, dead after M
  unsigned short* Wkl   = (unsigned short*)(ws + 34 * MB);
  unsigned short* Wqh   = (unsigned short*)(ws + 36 * MB);
  unsigned short* Wql   = (unsigned short*)(ws + 38 * MB);
  unsigned short* MTh   = (unsigned short*)(ws + 40 * MB);    // 2MB f16, dead after T
  unsigned short* WvT   = (unsigned short*)(ws + 44 * MB);    // 2MB f16, dead after V
  float*          MTpart= (float*)(ws + 46 * MB);             // 16MB f32, dead after reduce
  unsigned short* Xkh   = (unsigned short*)(ws + 64 * MB);    // 16MB f16, live thru scores
  unsigned short* Th    = (unsigned short*)(ws + 80 * MB);    // 16MB f16, live thru scores
  unsigned short* VT    = (unsigned short*)(ws + 96 * MB);    // 16MB f16, live thru PV
  float*          Sc    = (float*)(ws + 0);                   // 64MB alias over dead region

  // --- precision prep ---
  split_w_kernel<<<dim3(512, 1, 2), 256, 0, stream>>>(Wk, Wq, Wkh, Wkl, Wqh, Wql);
  convert_wv_kernel<<<dim3(16, 16), 256, 0, stream>>>(Wv, WvT);
  convert_x_kernel<<<dim3(2048, 1, 3), 256, 0, stream>>>(Xk, Xq, Xv, Xkh, Xqh, Xvh);

  // --- M^T = Wk . Wq^T (3-term bf16 split), split-K over 4 K-slices ---
  gemm_db_kernel<3, 0, false, false, false><<<dim3(8, 8, 4), 256, 0, stream>>>(
      Wkh, Wkl, Wqh, Wql, 1024, 1024, 256, MTpart, nullptr, nullptr, 1024,
      256, 256, (size_t)1024 * 1024);
  reduce_mt_kernel<<<dim3(1024), 256, 0, stream>>>(MTpart, MTh);

  // --- T = Xq_f16 . MT^T (1-term f16, f16 out) ---
  gemm_db_kernel<1, 2, false, false, true><<<dim3(8, 64, 1), 256, 0, stream>>>(
      Xqh, nullptr, MTh, nullptr, 1024, 1024, 1024, nullptr, Th, nullptr,
      1024, 0, 0, 0);

  // --- V = Xv . Wv (1-term f16), epilogue writes VT (f16) directly ---
  gemm_db_kernel<1, 3, false, false, true><<<dim3(8, 64, 1), 256, 0, stream>>>(
      Xvh, nullptr, WvT, nullptr, 1024, 1024, 1024, nullptr, VT, nullptr,
      2048, 0, 0, 0);

  // --- scores = T_f16 . Xk_f16^T (1-term f16), packed lower-triangle ---
  gemm_db_kernel<1, 0, true, false, true><<<dim3(136, 1, 4), 256, 0, stream>>>(
      Th, nullptr, Xkh, nullptr, 1024, 1024, 1024, Sc, nullptr, nullptr, 2048,
      (size_t)2048 * 1024, (size_t)2048 * 1024, (size_t)2048 * 2048);

  softmax_kernel<<<dim3(8192), 256, 0, stream>>>(Sc);

  // --- out = P_f16 . V (f16), P pitch 4096, VT K-major, K stops at diag;
  //     heavy (large-bm) tiles dispatch first ---
  gemm_db_kernel<1, 0, false, true, true><<<dim3(8, 16, 4), 256, 0, stream>>>(
      (const unsigned short*)Sc, nullptr, VT, nullptr, 4096, 2048, 2048,
      out, nullptr, nullptr, 1024, (size_t)2048 * 4096, (size_t)1024 * 2048,
      (size_t)2048 * 1024);
}

// Round 12
// 164.226 us; speedup vs baseline: 2.1242x; 1.0314x over previous
//
#include <hip/hip_runtime.h>
#include <math.h>

using f32x4  = __attribute__((ext_vector_type(4))) float;
using bf16x8 = __attribute__((ext_vector_type(8))) short;
using f16x8  = __attribute__((ext_vector_type(8))) _Float16;
using u16x8  = __attribute__((ext_vector_type(8))) unsigned short;
using u16x4  = __attribute__((ext_vector_type(4))) unsigned short;

static __device__ __forceinline__ unsigned short f2bf(float f) {
  unsigned int u = __builtin_bit_cast(unsigned int, f);
  u += 0x7FFFu + ((u >> 16) & 1u);
  return (unsigned short)(u >> 16);
}
static __device__ __forceinline__ float bf2f(unsigned short h) {
  unsigned int u = ((unsigned int)h) << 16;
  return __builtin_bit_cast(float, u);
}
static __device__ __forceinline__ unsigned short f2h(float f) {
  _Float16 h = (_Float16)f;
  return __builtin_bit_cast(unsigned short, h);
}

// dtype-dispatched 16x16x32 MFMA (C/D layout is dtype-independent, m89/m121)
template <bool F16>
static __device__ __forceinline__ f32x4 mfma16(bf16x8 a, bf16x8 b, f32x4 c) {
  if constexpr (F16)
    return __builtin_amdgcn_mfma_f32_16x16x32_f16(
        __builtin_bit_cast(f16x8, a), __builtin_bit_cast(f16x8, b), c, 0, 0, 0);
  else
    return __builtin_amdgcn_mfma_f32_16x16x32_bf16(a, b, c, 0, 0, 0);
}
template <bool F16>
static __device__ __forceinline__ unsigned short cvt16(float v) {
  if constexpr (F16) return f2h(v);
  else return f2bf(v);
}

// async global->LDS, 16B per lane. LDS dest is wave-uniform base; HW appends
// lane*16.
static __device__ __forceinline__ void gll16(const void* g, void* l) {
  using GPtr = const unsigned int __attribute__((address_space(1)))*;
  using LPtr = unsigned int __attribute__((address_space(3)))*;
  __builtin_amdgcn_global_load_lds((GPtr)(unsigned long long)g,
                                   (LPtr)(unsigned)(unsigned long long)l,
                                   16, 0, 0);
}

// Stage one [128][BK] 16-bit tile (rule #21: linear LDS dest, pre-swizzled
// global source). Wave w stages rows [32w, 32w+32).
// BK=64: rows are 128B lines; slot (16B) XOR row&7.        [r3+: 0-conflict]
// BK=32: PAIRED-ROW layout — 64 lines x 128B.              [r7: 0-conflict]
// Loads issued per wave per tile: BK=64 -> 4, BK=32 -> 2.
template <int BK>
static __device__ __forceinline__ void stageT(unsigned short* sdst,
                                              const unsigned short* g,
                                              size_t ld, int k0, int wave,
                                              int lane) {
  if constexpr (BK == 64) {
    const int r = lane >> 3, c8 = lane & 7;
    const int scol = (c8 ^ r) << 3;
#pragma unroll
    for (int i = 0; i < 4; ++i)
      gll16(g + (size_t)(wave * 32 + i * 8 + r) * ld + (k0 + scol),
            sdst + wave * 2048 + i * 512);
  } else {
    const int p = lane & 7;    // physical 16B slot in line
    const int ll = lane >> 3;  // local line 0..7
#pragma unroll
    for (int i = 0; i < 2; ++i) {
      const int line = wave * 16 + i * 8 + ll;  // global line 0..63
      const int q = p ^ (line & 7);
      const int srow = 2 * line + (q >> 2);
      const int scol = (q & 3) << 3;
      gll16(g + (size_t)srow * ld + (k0 + scol), sdst + wave * 1024 + i * 512);
    }
  }
}

// Swizzled fragment read matching stageT's layout.
template <int BK>
static __device__ __forceinline__ bf16x8 fragT(const unsigned short* s,
                                               int row, int kko) {
  if constexpr (BK == 64) {
    return *(const bf16x8*)&s[row * 64 + (kko ^ ((row & 7) << 3))];
  } else {
    const int line = row >> 1;
    const int q = ((row & 1) << 2) | (kko >> 3);
    const int p = q ^ (line & 7);
    return *(const bf16x8*)&s[line * 64 + p * 8];
  }
}

// ---------------------------------------------------------------------------
// Wk/Wq [1024x1024] f32 -> f16, original layout, fully coalesced.
// z: 0 = Wk, 1 = Wq. grid (256,1,2), 4096 elems/block.
// ---------------------------------------------------------------------------
__global__ __launch_bounds__(256) void convert_wkq_kernel(
    const float* __restrict__ Wk, const float* __restrict__ Wq,
    unsigned short* __restrict__ Wkh, unsigned short* __restrict__ Wqh) {
  const int z = blockIdx.z;
  const float* W = z ? Wq : Wk;
  unsigned short* H = z ? Wqh : Wkh;
  const size_t base = (size_t)blockIdx.x * 4096 + threadIdx.x * 4;
#pragma unroll
  for (int k = 0; k < 4; ++k) {
    f32x4 v = *(const f32x4*)&W[base + k * 1024];
    u16x4 h;
#pragma unroll
    for (int e = 0; e < 4; ++e) h[e] = f2h(v[e]);
    *(u16x4*)&H[base + k * 1024] = h;
  }
}

// ---------------------------------------------------------------------------
// Wv [1024 i][1024 o] f32 -> WvT [1024 o][1024 i] f16 (transposed)
// ---------------------------------------------------------------------------
__global__ __launch_bounds__(256) void convert_wv_kernel(
    const float* __restrict__ Wv, unsigned short* __restrict__ WvT) {
  __shared__ float sW[64][65];
  const int ti = blockIdx.x * 64;
  const int tj = blockIdx.y * 64;
  const int tid = threadIdx.x;
#pragma unroll
  for (int it = 0; it < 4; ++it) {
    int idx = tid + it * 256;
    int r = idx >> 4, c = (idx & 15) << 2;
    f32x4 v = *(const f32x4*)&Wv[(size_t)(ti + r) * 1024 + tj + c];
    sW[r][c] = v[0]; sW[r][c + 1] = v[1]; sW[r][c + 2] = v[2]; sW[r][c + 3] = v[3];
  }
  __syncthreads();
#pragma unroll
  for (int it = 0; it < 4; ++it) {
    int idx = tid + it * 256;
    int ro = idx >> 4, ci = (idx & 15) << 2;
    u16x4 h;
#pragma unroll
    for (int e = 0; e < 4; ++e) h[e] = f2h(sW[ci + e][ro]);
    *(u16x4*)&WvT[(size_t)(tj + ro) * 1024 + ti + ci] = h;
  }
}

// ---------------------------------------------------------------------------
// X [8192 x 1024] f32 -> X_f16, fully coalesced: lane handles 4 elems per
// instruction, 4 instructions at +1024-elem stride. Every wave load covers
// contiguous 1KB, every store 512B. z: 0 = keys, 1 = queries, 2 = values.
// grid (2048,1,3), 4096 elems/block.
// ---------------------------------------------------------------------------
__global__ __launch_bounds__(256) void convert_x_kernel(
    const float* __restrict__ Xk, const float* __restrict__ Xq,
    const float* __restrict__ Xv, unsigned short* __restrict__ Xkh,
    unsigned short* __restrict__ Xqh, unsigned short* __restrict__ Xvh) {
  const int z = blockIdx.z;
  const float* X = (z == 0) ? Xk : (z == 1) ? Xq : Xv;
  unsigned short* H = (z == 0) ? Xkh : (z == 1) ? Xqh : Xvh;
  const size_t base = (size_t)blockIdx.x * 4096 + threadIdx.x * 4;
#pragma unroll
  for (int k = 0; k < 4; ++k) {
    f32x4 v = *(const f32x4*)&X[base + k * 1024];
    u16x4 h;
#pragma unroll
    for (int e = 0; e < 4; ++e) h[e] = f2h(v[e]);
    *(u16x4*)&H[base + k * 1024] = h;
  }
}

// ---------------------------------------------------------------------------
// Unified 16-bit GEMM, deep 2-buffer counted-vmcnt pipeline (T4, r8-verified):
// prologue stages BOTH buffers; per step: vmcnt(LPS) -> barrier -> MFMA ->
// lgkmcnt(0) -> barrier -> restage for st+2. LPS: NTERMS 3 -> 8, 2 -> 6,
// 1 -> 8. NTERMS==3: BK=32 paired-row, 4 tiles/buf (64KB); NTERMS==2: BK=32,
// 3 tiles/buf (48KB); NTERMS==1: BK=64, 2 tiles/buf (64KB). XCD swizzle (T1).
// Terms: 3 = AhBh+AhBl+AlBh ; 2 = AhBh+AhBl ; 1 = AhBh.
// F16: use f16 MFMA + f16 epilogue converts (else bf16).
// EPI: 0 = f32 C ; 1 = 16b hi+lo ; 2 = 16b hi ; 3 = 16b transposed into
// VT[4][1024][2048] (fused V-transpose).
// PACKED: lid%gx is a packed lower-triangle tile index.
// PVK: K-loop ends at (bm+1)*128; bm decode is REVERSED so heavy tiles
// dispatch first (light diagonal blocks pack the tail).
// ---------------------------------------------------------------------------
template <int NTERMS, int EPI, bool PACKED, bool PVK, bool F16>
__global__ __launch_bounds__(256, 2) void gemm_db_kernel(
    const unsigned short* __restrict__ Ah, const unsigned short* __restrict__ Al,
    const unsigned short* __restrict__ Bh, const unsigned short* __restrict__ Bl,
    size_t lda, size_t ldb, int K,
    float* __restrict__ Cf, unsigned short* __restrict__ Ch,
    unsigned short* __restrict__ Cl, size_t ldc,
    size_t abatch, size_t bbatch, size_t cbatch) {
  constexpr int BK = (NTERMS >= 2) ? 32 : 64;
  constexpr int NTILES = (NTERMS == 3) ? 4 : (NTERMS == 2) ? 3 : 2;
  constexpr int TILE = 128 * BK;  // shorts per tile
  __shared__ unsigned short smem[2][NTILES * TILE];

  // Bijective XCD-chunked swizzle over the full linearized grid (m204).
  int lid = blockIdx.x + gridDim.x * (blockIdx.y + gridDim.y * blockIdx.z);
  {
    const int n = gridDim.x * gridDim.y * gridDim.z;
    const int q = n >> 3, r = n & 7, x = lid & 7, k = lid >> 3;
    lid = (x < r ? x * (q + 1) : r * (q + 1) + (x - r) * q) + k;
  }
  int bm, bn, b;
  if constexpr (PACKED) {
    const int t = lid % gridDim.x;
    b = lid / gridDim.x;
    bm = (int)((sqrtf(8.f * (float)t + 1.f) - 1.f) * 0.5f);
    while ((bm + 1) * (bm + 2) / 2 <= t) ++bm;
    while (bm * (bm + 1) / 2 > t) --bm;
    bn = t - bm * (bm + 1) / 2;
  } else {
    bn = lid % gridDim.x;
    const int tmp = lid / gridDim.x;
    bm = tmp % gridDim.y;
    b = tmp / gridDim.y;
    if constexpr (PVK) bm = (int)gridDim.y - 1 - bm;  // heavy tiles first
  }
  const int tid = threadIdx.x, lane = tid & 63, wave = tid >> 6;
  const unsigned short* gA = Ah + abatch * b + (size_t)(bm * 128) * lda;
  const unsigned short* gB = Bh + bbatch * b + (size_t)(bn * 128) * ldb;
  const unsigned short* gAl2 =
      (NTERMS == 3) ? Al + abatch * b + (size_t)(bm * 128) * lda : nullptr;
  const unsigned short* gBl2 =
      (NTERMS >= 2) ? Bl + bbatch * b + (size_t)(bn * 128) * ldb : nullptr;
  const int kend = PVK ? (bm + 1) * 128 : K;
  const int nsteps = kend / BK;
  f32x4 acc[4][4] = {};
  const int wr = (wave >> 1) << 6, wc = (wave & 1) << 6;
  const int frow = lane & 15, koff = (lane >> 4) << 3;

  auto stage_all = [&](unsigned short* buf, int k0) {
    stageT<BK>(buf, gA, lda, k0, wave, lane);
    stageT<BK>(buf + TILE, gB, ldb, k0, wave, lane);
    if constexpr (NTERMS >= 2) stageT<BK>(buf + 2 * TILE, gBl2, ldb, k0, wave, lane);
    if constexpr (NTERMS == 3) stageT<BK>(buf + 3 * TILE, gAl2, lda, k0, wave, lane);
  };

  stage_all(smem[0], 0);
  if (nsteps > 1) stage_all(smem[1], BK);
  int cur = 0;
  for (int st = 0; st < nsteps; ++st) {
    if (st + 1 < nsteps) {
      if constexpr (NTERMS == 2)
        asm volatile("s_waitcnt vmcnt(6)" ::: "memory");
      else
        asm volatile("s_waitcnt vmcnt(8)" ::: "memory");
    } else {
      asm volatile("s_waitcnt vmcnt(0)" ::: "memory");
    }
    __builtin_amdgcn_sched_barrier(0);
    __builtin_amdgcn_s_barrier();  // buf[cur] fully in LDS (all waves)
    __builtin_amdgcn_sched_barrier(0);
    const unsigned short* sA = smem[cur];
    const unsigned short* sB = smem[cur] + TILE;
    if constexpr (NTERMS >= 2) {
      const unsigned short* sBl = smem[cur] + 2 * TILE;
      const unsigned short* sAl = smem[cur] + 3 * TILE;  // NTERMS==3 only
      bf16x8 fBh[4], fBl[4];
#pragma unroll
      for (int j = 0; j < 4; ++j) {
        fBh[j] = fragT<BK>(sB, wc + j * 16 + frow, koff);
        fBl[j] = fragT<BK>(sBl, wc + j * 16 + frow, koff);
      }
#pragma unroll
      for (int i = 0; i < 4; ++i) {
        const bf16x8 ah = fragT<BK>(sA, wr + i * 16 + frow, koff);
        bf16x8 al = {};
        if constexpr (NTERMS == 3) al = fragT<BK>(sAl, wr + i * 16 + frow, koff);
#pragma unroll
        for (int j = 0; j < 4; ++j) {
          acc[i][j] = mfma16<F16>(ah, fBh[j], acc[i][j]);
          acc[i][j] = mfma16<F16>(ah, fBl[j], acc[i][j]);
          if constexpr (NTERMS == 3)
            acc[i][j] = mfma16<F16>(al, fBh[j], acc[i][j]);
        }
      }
    } else {
#pragma unroll
      for (int kk = 0; kk < 64; kk += 32) {
        const int kko = kk + koff;
        bf16x8 fBh[4];
#pragma unroll
        for (int j = 0; j < 4; ++j) fBh[j] = fragT<BK>(sB, wc + j * 16 + frow, kko);
#pragma unroll
        for (int i = 0; i < 4; ++i) {
          const bf16x8 ah = fragT<BK>(sA, wr + i * 16 + frow, kko);
#pragma unroll
          for (int j = 0; j < 4; ++j)
            acc[i][j] = mfma16<F16>(ah, fBh[j], acc[i][j]);
        }
      }
    }
    asm volatile("s_waitcnt lgkmcnt(0)" ::: "memory");
    __builtin_amdgcn_sched_barrier(0);
    __builtin_amdgcn_s_barrier();  // all waves done reading buf[cur]
    __builtin_amdgcn_sched_barrier(0);
    if (st + 2 < nsteps) stage_all(smem[cur], (st + 2) * BK);
    cur ^= 1;
  }

  const int erow = bm * 128 + wr + ((lane >> 4) << 2);
  const int ecol = bn * 128 + wc + frow;
  if constexpr (EPI == 0) {
    float* C = Cf + cbatch * b;
#pragma unroll
    for (int i = 0; i < 4; ++i)
#pragma unroll
      for (int j = 0; j < 4; ++j)
#pragma unroll
        for (int e = 0; e < 4; ++e)
          C[(size_t)(erow + i * 16 + e) * ldc + (ecol + j * 16)] = acc[i][j][e];
  } else if constexpr (EPI == 3) {
    // Fused V-transpose: Ch is VT[4][1024 o][2048 s].
#pragma unroll
    for (int i = 0; i < 4; ++i)
#pragma unroll
      for (int j = 0; j < 4; ++j) {
        const int s = erow + i * 16;
        const int o = ecol + j * 16;
        u16x4 v;
#pragma unroll
        for (int e = 0; e < 4; ++e) v[e] = cvt16<F16>(acc[i][j][e]);
        *(u16x4*)&Ch[((size_t)(s >> 11) * 1024 + o) * 2048 + (s & 2047)] = v;
      }
  } else {
    unsigned short* Cho = Ch + cbatch * b;
    unsigned short* Clo = (EPI == 1) ? Cl + cbatch * b : nullptr;
#pragma unroll
    for (int i = 0; i < 4; ++i)
#pragma unroll
      for (int j = 0; j < 4; ++j)
#pragma unroll
        for (int e = 0; e < 4; ++e) {
          size_t off = (size_t)(erow + i * 16 + e) * ldc + (ecol + j * 16);
          float v = acc[i][j][e];
          unsigned short hh = cvt16<F16>(v);
          Cho[off] = hh;
          if constexpr (EPI == 1) Clo[off] = f2bf(v - bf2f(hh));
        }
  }
}

// ---------------------------------------------------------------------------
// Sum 4 split-K partials of MT (f32) -> MT plain f16. [1024x1024]
// ---------------------------------------------------------------------------
__global__ __launch_bounds__(256) void reduce_mt_kernel(
    const float* __restrict__ P, unsigned short* __restrict__ H) {
  const size_t base = ((size_t)blockIdx.x * 256 + threadIdx.x) * 4;
  f32x4 s = *(const f32x4*)&P[base];
#pragma unroll
  for (int z = 1; z < 4; ++z) {
    f32x4 v = *(const f32x4*)&P[(size_t)z * 1048576 + base];
    s[0] += v[0]; s[1] += v[1]; s[2] += v[2]; s[3] += v[3];
  }
  u16x4 h;
#pragma unroll
  for (int e = 0; e < 4; ++e) h[e] = f2h(s[e]);
  *(u16x4*)&H[base] = h;
}

// ---------------------------------------------------------------------------
// Row softmax with causal mask + 1/sqrt(d) scale. Writes f16 P in-place
// over the f32 scores buffer. Safe: reads complete before first barrier.
// ---------------------------------------------------------------------------
__global__ __launch_bounds__(256) void softmax_kernel(float* __restrict__ Sc) {
  const int row = blockIdx.x;  // b*2048 + q
  const int q = row & 2047;
  const int tid = threadIdx.x, lane = tid & 63, wave = tid >> 6;
  float* srow = Sc + (size_t)row * 2048;
  unsigned short* prow = (unsigned short*)srow;
  const int k0 = tid * 4, k1 = 1024 + tid * 4;
  f32x4 v0 = {}, v1 = {};
  if (k0 <= q) v0 = *(const f32x4*)(srow + k0);
  if (k1 <= q) v1 = *(const f32x4*)(srow + k1);
  float m = -3.0e38f;
#pragma unroll
  for (int e = 0; e < 4; ++e) {
    if (k0 + e <= q) m = fmaxf(m, v0[e]);
    if (k1 + e <= q) m = fmaxf(m, v1[e]);
  }
#pragma unroll
  for (int o = 32; o; o >>= 1) m = fmaxf(m, __shfl_xor(m, o));
  __shared__ float redm[4], reds[4];
  if (lane == 0) redm[wave] = m;
  __syncthreads();
  m = fmaxf(fmaxf(redm[0], redm[1]), fmaxf(redm[2], redm[3]));
  const float scale = 0.03125f;  // 1/sqrt(1024)
  float p[8];
  float s = 0.f;
#pragma unroll
  for (int e = 0; e < 4; ++e) {
    p[e] = (k0 + e <= q) ? __expf((v0[e] - m) * scale) : 0.f;
    p[4 + e] = (k1 + e <= q) ? __expf((v1[e] - m) * scale) : 0.f;
    s += p[e] + p[4 + e];
  }
#pragma unroll
  for (int o = 32; o; o >>= 1) s += __shfl_xor(s, o);
  if (lane == 0) reds[wave] = s;
  __syncthreads();
  s = reds[0] + reds[1] + reds[2] + reds[3];
  const float inv = 1.0f / s;
  u16x4 o0, o1;
#pragma unroll
  for (int e = 0; e < 4; ++e) {
    o0[e] = f2h(p[e] * inv);
    o1[e] = f2h(p[4 + e] * inv);
  }
  *(u16x4*)&prow[k0] = o0;
  *(u16x4*)&prow[k1] = o1;
}

// ---------------------------------------------------------------------------
extern "C" void kernel_launch(void* const* d_in, const int* in_sizes, int n_in,
                              void* d_out, int out_size, void* d_ws, size_t ws_size,
                              hipStream_t stream) {
  const float* Xk = (const float*)d_in[0];
  const float* Xv = (const float*)d_in[1];
  const float* Xq = (const float*)d_in[2];
  const float* Wk = (const float*)d_in[3];
  const float* Wv = (const float*)d_in[4];
  const float* Wq = (const float*)d_in[5];
  float* out = (float*)d_out;

  char* ws = (char*)d_ws;
  const size_t MB = 1024ull * 1024;
  // Liveness: everything in [0,64MB) is dead before scores -> Sc alias.
  unsigned short* Xqh   = (unsigned short*)(ws + 0);          // 16MB f16, dead after T
  unsigned short* Xvh   = (unsigned short*)(ws + 16 * MB);    // 16MB f16, dead after V
  unsigned short* Wkh   = (unsigned short*)(ws + 32 * MB);    // 2MB f16, dead after M
  unsigned short* Wqh   = (unsigned short*)(ws + 34 * MB);    // 2MB f16, dead after M
  unsigned short* MTh   = (unsigned short*)(ws + 40 * MB);    // 2MB f16, dead after T
  unsigned short* WvT   = (unsigned short*)(ws + 44 * MB);    // 2MB f16, dead after V
  float*          MTpart= (float*)(ws + 46 * MB);             // 16MB f32, dead after reduce
  unsigned short* Xkh   = (unsigned short*)(ws + 64 * MB);    // 16MB f16, live thru scores
  unsigned short* Th    = (unsigned short*)(ws + 80 * MB);    // 16MB f16, live thru scores
  unsigned short* VT    = (unsigned short*)(ws + 96 * MB);    // 16MB f16, live thru PV
  float*          Sc    = (float*)(ws + 0);                   // 64MB alias over dead region

  // --- precision prep (all f16) ---
  convert_wkq_kernel<<<dim3(256, 1, 2), 256, 0, stream>>>(Wk, Wq, Wkh, Wqh);
  convert_wv_kernel<<<dim3(16, 16), 256, 0, stream>>>(Wv, WvT);
  convert_x_kernel<<<dim3(2048, 1, 3), 256, 0, stream>>>(Xk, Xq, Xv, Xkh, Xqh, Xvh);

  // --- M^T = Wk_f16 . Wq_f16^T (1-term f16), split-K over 4 256-wide slices ---
  gemm_db_kernel<1, 0, false, false, true><<<dim3(8, 8, 4), 256, 0, stream>>>(
      Wkh, nullptr, Wqh, nullptr, 1024, 1024, 256, MTpart, nullptr, nullptr,
      1024, 256, 256, (size_t)1024 * 1024);
  reduce_mt_kernel<<<dim3(1024), 256, 0, stream>>>(MTpart, MTh);

  // --- T = Xq_f16 . MT^T (1-term f16, f16 out) ---
  gemm_db_kernel<1, 2, false, false, true><<<dim3(8, 64, 1), 256, 0, stream>>>(
      Xqh, nullptr, MTh, nullptr, 1024, 1024, 1024, nullptr, Th, nullptr,
      1024, 0, 0, 0);

  // --- V = Xv . Wv (1-term f16), epilogue writes VT (f16) directly ---
  gemm_db_kernel<1, 3, false, false, true><<<dim3(8, 64, 1), 256, 0, stream>>>(
      Xvh, nullptr, WvT, nullptr, 1024, 1024, 1024, nullptr, VT, nullptr,
      2048, 0, 0, 0);

  // --- scores = T_f16 . Xk_f16^T (1-term f16), packed lower-triangle ---
  gemm_db_kernel<1, 0, true, false, true><<<dim3(136, 1, 4), 256, 0, stream>>>(
      Th, nullptr, Xkh, nullptr, 1024, 1024, 1024, Sc, nullptr, nullptr, 2048,
      (size_t)2048 * 1024, (size_t)2048 * 1024, (size_t)2048 * 2048);

  softmax_kernel<<<dim3(8192), 256, 0, stream>>>(Sc);

  // --- out = P_f16 . V (f16), P pitch 4096, VT K-major, K stops at diag;
  //     heavy (large-bm) tiles dispatch first ---
  gemm_db_kernel<1, 0, false, true, true><<<dim3(8, 16, 4), 256, 0, stream>>>(
      (const unsigned short*)Sc, nullptr, VT, nullptr, 4096, 2048, 2048,
      out, nullptr, nullptr, 1024, (size_t)2048 * 4096, (size_t)1024 * 2048,
      (size_t)2048 * 1024);
}